// Round 8
// baseline (2064.665 us; speedup 1.0000x reference)
//
#include <hip/hip_runtime.h>

#define EPSV  1e-20f
#define BNEPS 1e-5f

typedef _Float16 f16x8 __attribute__((ext_vector_type(8)));
typedef _Float16 f16x4 __attribute__((ext_vector_type(4)));
typedef float    f32x4 __attribute__((ext_vector_type(4)));

__device__ inline unsigned pack2f16(float a, float b) {
    unsigned short ua = __builtin_bit_cast(unsigned short, (_Float16)a);
    unsigned short ub = __builtin_bit_cast(unsigned short, (_Float16)b);
    return ((unsigned)ub << 16) | ua;
}

// ---------------------------------------------------------------------------
// Weight prep (blocks 1/2): wn = |w|/(sum+eps), f16 GEMM layouts
//   wBh[tap][co][ci]  (update conv: n=co, k=ci)
//   wAh[tapf][ci][co] (ratio conv:  n=ci, k=co)
// ---------------------------------------------------------------------------
template<int CIN, int COUT>
__global__ __launch_bounds__(256) void prep_w_f16_kernel(const float* __restrict__ w,
                                                         _Float16* __restrict__ wAh,
                                                         _Float16* __restrict__ wBh)
{
    const int co  = blockIdx.x;
    const int tid = threadIdx.x;
    const int N   = CIN * 9;
    const float* wrow = w + (size_t)co * N;

    float s = 0.f;
    for (int i = tid; i < N; i += 256) s += fabsf(wrow[i]);
    __shared__ float red[4];
    #pragma unroll
    for (int m = 32; m; m >>= 1) s += __shfl_xor(s, m, 64);
    if ((tid & 63) == 0) red[tid >> 6] = s;
    __syncthreads();
    s = red[0] + red[1] + red[2] + red[3];
    const float rn = 1.f / (s + EPSV);

    for (int i = tid; i < N; i += 256) {
        const int ci = i / 9, tap = i % 9;
        const int ky = tap / 3, kx = tap % 3;
        const float v = fabsf(wrow[i]) * rn;
        const int tf = (2 - ky) * 3 + (2 - kx);
        wBh[((size_t)tap * COUT + co) * CIN + ci] = (_Float16)v;
        wAh[((size_t)tf * CIN + ci) * COUT + co] = (_Float16)v;
    }
}

// Block0 weight prep: wB0h[co][tap*4+ci] (K=36 pad 64), wA0h[tapf][ci(16p)][co(64)]
__global__ __launch_bounds__(256) void zero_f16_kernel(_Float16* __restrict__ a, int n)
{
    const int i = blockIdx.x * 256 + threadIdx.x;
    if (i < n) a[i] = (_Float16)0.f;
}

__global__ __launch_bounds__(64) void prep_w0_kernel(const float* __restrict__ w,
                                                     _Float16* __restrict__ wA0h,
                                                     _Float16* __restrict__ wB0h)
{
    const int co = blockIdx.x, tid = threadIdx.x;  // 64 threads, 1 wave
    float s = (tid < 27) ? fabsf(w[co * 27 + tid]) : 0.f;
    #pragma unroll
    for (int m = 32; m; m >>= 1) s += __shfl_xor(s, m, 64);
    const float rn = 1.f / (s + EPSV);
    if (tid < 27) {
        const int ci = tid / 9, tap = tid % 9, ky = tap / 3, kx = tap % 3;
        const float v = fabsf(w[co * 27 + tid]) * rn;
        wB0h[co * 64 + tap * 4 + ci] = (_Float16)v;
        wA0h[(((2 - ky) * 3 + (2 - kx)) * 16 + ci) * 64 + co] = (_Float16)v;
    }
}

__global__ __launch_bounds__(256) void prep_w1h_kernel(const float* __restrict__ w1,
                                                       _Float16* __restrict__ w1h, int n)
{
    const int i = blockIdx.x * 256 + threadIdx.x;
    if (i < n) w1h[i] = (_Float16)w1[i];
}

// ---------------------------------------------------------------------------
// xn prep.
// ---------------------------------------------------------------------------
__global__ __launch_bounds__(256) void xn0_kernel(const float* __restrict__ x,
                                                  _Float16* __restrict__ xn4,
                                                  int npx, int HW)
{
    const int p = blockIdx.x * 256 + threadIdx.x;
    if (p >= npx) return;
    const int b = p / HW, r = p % HW;
    const float* ip = x + (size_t)b * 3 * HW + r;
    const float v0 = fmaxf(ip[0], 0.f), v1 = fmaxf(ip[HW], 0.f), v2 = fmaxf(ip[2 * HW], 0.f);
    const float rs = 1.f / (v0 + v1 + v2 + EPSV);
    unsigned* d = (unsigned*)(xn4 + (size_t)p * 4);
    d[0] = pack2f16(v0 * rs, v1 * rs);
    d[1] = pack2f16(v2 * rs, 0.f);
}

template<int C>
__global__ __launch_bounds__(256) void xn12_kernel(const _Float16* __restrict__ prev,
                                                   _Float16* __restrict__ xn, int npx)
{
    const int p = blockIdx.x * 256 + threadIdx.x;
    if (p >= npx) return;
    const _Float16* ip = prev + (size_t)p * C;
    _Float16* op = xn + (size_t)p * C;
    f16x8 buf[C / 8];
    float s = 0.f;
    #pragma unroll
    for (int g = 0; g < C / 8; ++g) {
        buf[g] = *(const f16x8*)(ip + g * 8);
        #pragma unroll
        for (int j = 0; j < 8; ++j) {
            float v = fmaxf((float)buf[g][j], 0.f);
            s += v;
            buf[g][j] = (_Float16)v;
        }
    }
    const float rs = 1.f / (s + EPSV);
    #pragma unroll
    for (int g = 0; g < C / 8; ++g) {
        f16x8 o;
        #pragma unroll
        for (int j = 0; j < 8; ++j) o[j] = (_Float16)((float)buf[g][j] * rs);
        *(f16x8*)(op + g * 8) = o;
    }
}

__global__ __launch_bounds__(256) void init_h_kernel(_Float16* __restrict__ h, float* __restrict__ S,
                                                     int nh, int ns, float cval)
{
    const int i = blockIdx.x * 256 + threadIdx.x;
    if (i < nh) h[i] = (_Float16)1.f;
    if (i < ns) S[i] = cval;
}

template<int NS>
__global__ __launch_bounds__(256) void combine_S_kernel(const float* __restrict__ sp,
                                                        float* __restrict__ S, int npx)
{
    const int i = blockIdx.x * 256 + threadIdx.x;
    if (i >= npx) return;
    float s = sp[i];
    #pragma unroll
    for (int k = 1; k < NS; ++k) s += sp[(size_t)k * npx + i];
    S[i] = s;
}

// ---------------------------------------------------------------------------
// mfconv3: NHWC f16 MFMA implicit-GEMM 3x3 'same' conv.
//   FULL input tile (all ICg channels, halo) staged in LDS once -> ONE barrier.
//   K-loop fully unrolled; B-frags hoisted per tap-row (3xNF loads issued
//   before their MFMAs) so L2 latency pipelines under compute.
//   NORM_IN: staged input scaled by 1/(Sin+eps) (ratio conv, in = h).
//   !UPDATE: out = aux/(acc+eps) f16, stride OST, only oc<NW written.
//   UPDATE : h f16 RMW (*= acc), S partials (split k: at split*sstride).
// Weights: wgt[tap][n(OCg)][k(ICg)] f16.  LDS row pad +8 f16 => <=2-way banks.
// ---------------------------------------------------------------------------
template<int ICg, int OCg, int TH, int TW, int NSPLIT, int OST, int NW,
         bool NORM_IN, bool UPDATE>
__global__ __launch_bounds__(256) void mfconv3(
    const _Float16* __restrict__ in, const _Float16* __restrict__ wgt,
    const _Float16* __restrict__ aux, _Float16* __restrict__ out,
    const float* __restrict__ Sin, float* __restrict__ Sout,
    int H, int W, int sstride)
{
    constexpr int OCWG = OCg / NSPLIT;
    constexpr int NF = OCWG / 16;
    constexpr int HS = TH + 2, WSp = TW + 2, NSP = HS * WSp;
    constexpr int ICP = ICg + 8;
    constexpr int NCH = ICg / 32;
    constexpr int LS = (NSPLIT == 4) ? 2 : (NSPLIT == 2) ? 1 : 0;
    constexpr int C8 = ICg / 8;
    constexpr int NLD = NSP * C8;
    constexpr int IREG = (NLD + 255) / 256;
    static_assert(TH * TW == 64 && OCWG % 16 == 0 && ICg % 32 == 0, "cfg");

    __shared__ _Float16 in_t[NSP * ICP];
    __shared__ float rS[NORM_IN ? NSP : 1];

    const int tid = threadIdx.x;
    const int lane = tid & 63, wave = tid >> 6;
    const int kq = lane >> 4, l15 = lane & 15;
    const int split = blockIdx.x & (NSPLIT - 1);
    const int tx = blockIdx.x >> LS;
    const int x0 = tx * TW, y0 = blockIdx.y * TH, b = blockIdx.z;
    const int HW = H * W;
    const int oc0 = split * OCWG;

    // ---- issue ALL input loads into regs (deep pipeline) ----
    f16x8 ld[IREG];
    #pragma unroll
    for (int r = 0; r < IREG; ++r) {
        const int i = tid + r * 256;
        f16x8 v = {0, 0, 0, 0, 0, 0, 0, 0};
        if (i < NLD) {
            const int sp = i / C8, seg = i % C8;
            const int yy = y0 + sp / WSp - 1, xx = x0 + sp % WSp - 1;
            if (yy >= 0 && yy < H && xx >= 0 && xx < W)
                v = *(const f16x8*)(in +
                    ((size_t)b * HW + (size_t)yy * W + xx) * ICg + seg * 8);
        }
        ld[r] = v;
    }
    if constexpr (NORM_IN) {
        for (int i = tid; i < NSP; i += 256) {
            const int yy = y0 + i / WSp - 1, xx = x0 + i % WSp - 1;
            float sv = 0.f;
            if (yy >= 0 && yy < H && xx >= 0 && xx < W)
                sv = Sin[(size_t)b * HW + (size_t)yy * W + xx];
            rS[i] = 1.f / (sv + EPSV);
        }
        __syncthreads();
    }
    // ---- LDS write (normalize while converting if needed) ----
    #pragma unroll
    for (int r = 0; r < IREG; ++r) {
        const int i = tid + r * 256;
        if (i < NLD) {
            const int sp = i / C8, seg = i % C8;
            if constexpr (NORM_IN) {
                const float f = rS[sp];
                unsigned* d = (unsigned*)&in_t[sp * ICP + seg * 8];
                d[0] = pack2f16((float)ld[r][0] * f, (float)ld[r][1] * f);
                d[1] = pack2f16((float)ld[r][2] * f, (float)ld[r][3] * f);
                d[2] = pack2f16((float)ld[r][4] * f, (float)ld[r][5] * f);
                d[3] = pack2f16((float)ld[r][6] * f, (float)ld[r][7] * f);
            } else {
                *(f16x8*)&in_t[sp * ICP + seg * 8] = ld[r];
            }
        }
    }
    __syncthreads();

    const int m = wave * 16 + l15;
    const int pyl = m / TW, pxl = m % TW;

    f32x4 acc[NF];
    #pragma unroll
    for (int nf = 0; nf < NF; ++nf) acc[nf] = (f32x4){0.f, 0.f, 0.f, 0.f};

    // ---- fully-unrolled K loop; B-frags hoisted per tap-row ----
    #pragma unroll
    for (int kc = 0; kc < NCH; ++kc) {
        #pragma unroll
        for (int dy = 0; dy < 3; ++dy) {
            f16x8 bfr[3][NF];
            #pragma unroll
            for (int dx = 0; dx < 3; ++dx) {
                const int tap = dy * 3 + dx;
                #pragma unroll
                for (int nf = 0; nf < NF; ++nf) {
                    const int oc = oc0 + nf * 16 + l15;
                    bfr[dx][nf] = *(const f16x8*)(
                        wgt + ((size_t)tap * OCg + oc) * ICg + kc * 32 + kq * 8);
                }
            }
            #pragma unroll
            for (int dx = 0; dx < 3; ++dx) {
                const int sp = (pyl + dy) * WSp + pxl + dx;
                const f16x8 afr = *(const f16x8*)&in_t[sp * ICP + kc * 32 + kq * 8];
                #pragma unroll
                for (int nf = 0; nf < NF; ++nf)
                    acc[nf] = __builtin_amdgcn_mfma_f32_16x16x32_f16(afr, bfr[dx][nf], acc[nf], 0, 0, 0);
            }
        }
    }

    // ---- epilogue ----
    const int pl = wave * 16 + kq * 4;
    const int py0 = pl / TW, px0 = pl % TW;
    const size_t pixbase = (size_t)b * HW + (size_t)(y0 + py0) * W + x0 + px0;

    if constexpr (!UPDATE) {
        #pragma unroll
        for (int nf = 0; nf < NF; ++nf) {
            const int oc = oc0 + nf * 16 + l15;
            if (oc < NW) {
                #pragma unroll
                for (int r = 0; r < 4; ++r) {
                    const size_t idx = (pixbase + r) * OST + oc;
                    out[idx] = (_Float16)((float)aux[idx] / (acc[nf][r] + EPSV));
                }
            }
        }
    } else {
        float s[4] = {0.f, 0.f, 0.f, 0.f};
        #pragma unroll
        for (int nf = 0; nf < NF; ++nf) {
            const int oc = oc0 + nf * 16 + l15;
            #pragma unroll
            for (int r = 0; r < 4; ++r) {
                const size_t idx = (pixbase + r) * OST + oc;
                const float hv = (float)out[idx] * acc[nf][r];
                const _Float16 hq = (_Float16)hv;
                out[idx] = hq;
                s[r] += (float)hq;
            }
        }
        #pragma unroll
        for (int mm = 1; mm < 16; mm <<= 1) {
            #pragma unroll
            for (int r = 0; r < 4; ++r) s[r] += __shfl_xor(s[r], mm);
        }
        if (l15 == 0) {
            float* sp_ = Sout + (size_t)split * sstride + pixbase;
            sp_[0] = s[0]; sp_[1] = s[1]; sp_[2] = s[2]; sp_[3] = s[3];
        }
    }
}

// ---------------------------------------------------------------------------
// Block0 update conv (3 -> 64) via im2col MFMA, h f16 RMW.
// ---------------------------------------------------------------------------
__global__ __launch_bounds__(256) void mf0u_kernel(
    const _Float16* __restrict__ ratio4, const _Float16* __restrict__ wB0h,
    _Float16* __restrict__ h, float* __restrict__ Sout, int H, int W)
{
    constexpr int TW = 16;
    __shared__ _Float16 a_t[64 * 72];

    const int tid = threadIdx.x;
    const int lane = tid & 63, wave = tid >> 6;
    const int kq = lane >> 4, l15 = lane & 15;
    const int x0 = blockIdx.x * TW, y0 = blockIdx.y * 4, b = blockIdx.z;
    const int HW = H * W;

    for (int i = tid; i < 64 * 72 / 2; i += 256) ((unsigned*)a_t)[i] = 0;
    __syncthreads();
    for (int i = tid; i < 576; i += 256) {
        const int px = i / 9, tap = i % 9;
        const int py = px / TW, pxx = px % TW;
        const int yy = y0 + py + tap / 3 - 1, xx = x0 + pxx + tap % 3 - 1;
        if (yy >= 0 && yy < H && xx >= 0 && xx < W)
            *(f16x4*)&a_t[px * 72 + tap * 4] =
                *(const f16x4*)(ratio4 + ((size_t)b * HW + (size_t)yy * W + xx) * 4);
    }
    __syncthreads();

    f32x4 acc[4];
    #pragma unroll
    for (int nf = 0; nf < 4; ++nf) acc[nf] = (f32x4){0.f, 0.f, 0.f, 0.f};
    #pragma unroll
    for (int kc = 0; kc < 2; ++kc) {
        const f16x8 afr = *(const f16x8*)&a_t[(wave * 16 + l15) * 72 + kc * 32 + kq * 8];
        #pragma unroll
        for (int nf = 0; nf < 4; ++nf) {
            const f16x8 bfr = *(const f16x8*)(wB0h + (size_t)(nf * 16 + l15) * 64 + kc * 32 + kq * 8);
            acc[nf] = __builtin_amdgcn_mfma_f32_16x16x32_f16(afr, bfr, acc[nf], 0, 0, 0);
        }
    }

    const int pl = wave * 16 + kq * 4;
    const size_t pixbase = (size_t)b * HW + (size_t)(y0 + pl / TW) * W + x0 + pl % TW;
    float s[4] = {0.f, 0.f, 0.f, 0.f};
    #pragma unroll
    for (int nf = 0; nf < 4; ++nf) {
        const int oc = nf * 16 + l15;
        #pragma unroll
        for (int r = 0; r < 4; ++r) {
            const size_t idx = (pixbase + r) * 64 + oc;
            const float hv = (float)h[idx] * acc[nf][r];
            const _Float16 hq = (_Float16)hv;
            h[idx] = hq;
            s[r] += (float)hq;
        }
    }
    #pragma unroll
    for (int mm = 1; mm < 16; mm <<= 1) {
        #pragma unroll
        for (int r = 0; r < 4; ++r) s[r] += __shfl_xor(s[r], mm);
    }
    if (l15 == 0) {
        float* sp_ = Sout + pixbase;
        sp_[0] = s[0]; sp_[1] = s[1]; sp_[2] = s[2]; sp_[3] = s[3];
    }
}

// ---------------------------------------------------------------------------
// posty (MFMA 1x1 conv), two-pass; h f16. Tile = 2 rows x 32 cols.
//   MODE 0: stats partials. MODE 1: pool+BN -> f16 NHWC. MODE 2: fp32 NCHW.
// ---------------------------------------------------------------------------
template<int C, int MODE>
__global__ __launch_bounds__(256) void posty_kernel(
    const _Float16* __restrict__ h, const float* __restrict__ S,
    const _Float16* __restrict__ w1h, const float* __restrict__ bias,
    const float* __restrict__ bnst, float* __restrict__ part,
    void* __restrict__ outp, int H, int W)
{
    constexpr int NF = C / 16, CP = C + 8;
    __shared__ _Float16 a_t[64 * CP];
    __shared__ float rs_t[64];
    __shared__ float sred1[MODE == 0 ? 4 * C : 1];
    __shared__ float sred2[MODE == 0 ? 4 * C : 1];

    const int tid = threadIdx.x;
    const int lane = tid & 63, wave = tid >> 6;
    const int kq = lane >> 4, l15 = lane & 15;
    const int WT = W / 32;
    const int tx = blockIdx.x % WT, ty = blockIdx.x / WT;
    const int b = blockIdx.y;
    const int HW = H * W;

    if (tid < 64) {
        const int gp = (2 * ty + (tid >> 5)) * W + tx * 32 + (tid & 31);
        rs_t[tid] = 1.f / (S[(size_t)b * HW + gp] + EPSV);
    }
    __syncthreads();
    for (int i = tid; i < 64 * (C / 8); i += 256) {
        const int sp = i / (C / 8), seg = i % (C / 8);
        const int gp = (2 * ty + (sp >> 5)) * W + tx * 32 + (sp & 31);
        const f16x8 v = *(const f16x8*)(h + ((size_t)b * HW + gp) * C + seg * 8);
        const float f = rs_t[sp];
        unsigned* d = (unsigned*)&a_t[sp * CP + seg * 8];
        d[0] = pack2f16((float)v[0] * f, (float)v[1] * f);
        d[1] = pack2f16((float)v[2] * f, (float)v[3] * f);
        d[2] = pack2f16((float)v[4] * f, (float)v[5] * f);
        d[3] = pack2f16((float)v[6] * f, (float)v[7] * f);
    }
    __syncthreads();

    f32x4 acc[NF];
    #pragma unroll
    for (int nf = 0; nf < NF; ++nf) acc[nf] = (f32x4){0.f, 0.f, 0.f, 0.f};
    #pragma unroll
    for (int kc = 0; kc < C / 32; ++kc) {
        const f16x8 afr = *(const f16x8*)&a_t[(wave * 16 + l15) * CP + kc * 32 + kq * 8];
        #pragma unroll
        for (int nf = 0; nf < NF; ++nf) {
            const f16x8 bfr = *(const f16x8*)(w1h + (size_t)(nf * 16 + l15) * C + kc * 32 + kq * 8);
            acc[nf] = __builtin_amdgcn_mfma_f32_16x16x32_f16(afr, bfr, acc[nf], 0, 0, 0);
        }
    }

    const int pl = wave * 16 + kq * 4;

    if constexpr (MODE == 0) {
        const int wgid = b * gridDim.x + blockIdx.x;
        #pragma unroll
        for (int nf = 0; nf < NF; ++nf) {
            const int oc = nf * 16 + l15;
            const float bv = bias[oc];
            float s1 = 0.f, s2 = 0.f;
            #pragma unroll
            for (int r = 0; r < 4; ++r) {
                const float y = fmaxf(acc[nf][r] + bv, 0.f);
                s1 += y; s2 += y * y;
            }
            s1 += __shfl_xor(s1, 16); s2 += __shfl_xor(s2, 16);
            s1 += __shfl_xor(s1, 32); s2 += __shfl_xor(s2, 32);
            if (kq == 0) {
                sred1[wave * C + oc] = s1;
                sred2[wave * C + oc] = s2;
            }
        }
        __syncthreads();
        for (int oc = tid; oc < C; oc += 256) {
            const float s1 = sred1[oc] + sred1[C + oc] + sred1[2 * C + oc] + sred1[3 * C + oc];
            const float s2 = sred2[oc] + sred2[C + oc] + sred2[2 * C + oc] + sred2[3 * C + oc];
            part[((size_t)wgid * C + oc) * 2 + 0] = s1;
            part[((size_t)wgid * C + oc) * 2 + 1] = s2;
        }
    } else {
        __syncthreads();        // all A-reads complete; reuse a_t for Y
        #pragma unroll
        for (int nf = 0; nf < NF; ++nf) {
            const int oc = nf * 16 + l15;
            const float bv = bias[oc];
            #pragma unroll
            for (int r = 0; r < 4; ++r)
                a_t[(pl + r) * CP + oc] = (_Float16)fmaxf(acc[nf][r] + bv, 0.f);
        }
        __syncthreads();
        const int Wo = W >> 1;
        for (int i = tid; i < 16 * C; i += 256) {
            int ox, c;
            if constexpr (MODE == 1) { c = i % C; ox = i / C; }
            else                     { ox = i % 16; c = i / 16; }
            const float y00 = (float)a_t[(2 * ox) * CP + c];
            const float y01 = (float)a_t[(2 * ox + 1) * CP + c];
            const float y10 = (float)a_t[(32 + 2 * ox) * CP + c];
            const float y11 = (float)a_t[(32 + 2 * ox + 1) * CP + c];
            const float v = (y00 + y01 + y10 + y11) * 0.25f * bnst[c] + bnst[C + c];
            if constexpr (MODE == 1) {
                ((_Float16*)outp)[((size_t)b * (HW >> 2) + (size_t)ty * Wo + tx * 16 + ox) * C + c] =
                    (_Float16)v;
            } else {
                ((float*)outp)[(((size_t)b * C + c) * (size_t)(H >> 1) + ty) * Wo + tx * 16 + ox] = v;
            }
        }
    }
}

// Reduce partials -> per-channel (scale, shift) for BN affine.
template<int C>
__global__ __launch_bounds__(256) void stats_kernel(const float* __restrict__ part, int nwg, float invM,
                                                    const float* __restrict__ gamma,
                                                    const float* __restrict__ beta,
                                                    float* __restrict__ stats)
{
    const int oc = blockIdx.x;
    const int tid = threadIdx.x;
    float s1 = 0.f, s2 = 0.f;
    for (int w = tid; w < nwg; w += 256) {
        s1 += part[((size_t)w * C + oc) * 2 + 0];
        s2 += part[((size_t)w * C + oc) * 2 + 1];
    }
    __shared__ float r1[4], r2[4];
    #pragma unroll
    for (int m = 32; m; m >>= 1) { s1 += __shfl_xor(s1, m, 64); s2 += __shfl_xor(s2, m, 64); }
    if ((tid & 63) == 0) { r1[tid >> 6] = s1; r2[tid >> 6] = s2; }
    __syncthreads();
    if (tid == 0) {
        s1 = r1[0] + r1[1] + r1[2] + r1[3];
        s2 = r2[0] + r2[1] + r2[2] + r2[3];
        const float mean = s1 * invM;
        const float var  = s2 * invM - mean * mean;
        const float rstd = rsqrtf(var + BNEPS);
        const float scale = gamma[oc] * rstd;
        stats[oc]     = scale;
        stats[C + oc] = beta[oc] - mean * scale;
    }
}

// ---------------------------------------------------------------------------
extern "C" void kernel_launch(void* const* d_in, const int* in_sizes, int n_in,
                              void* d_out, int out_size, void* d_ws, size_t ws_size,
                              hipStream_t stream)
{
    const float* x = (const float*)d_in[0];
    float* ws      = (float*)d_ws;
    float* S       = ws;                    //    262,144 f32
    float* part    = S + 262144;            //  1,048,576 f32
    float* bnstats = part + 1048576;        //        512 f32
    _Float16* h      = (_Float16*)(bnstats + 512); // 16,777,216 f16
    _Float16* xnh    = h + 16777216;               //  4,194,304 f16
    _Float16* ratioh = xnh + 4194304;              //  4,194,304 f16
    _Float16* out0h  = ratioh + 4194304;           //  4,194,304 f16
    _Float16* out1h  = out0h + 4194304;            //  2,097,152 f16
    _Float16* wAh    = out1h + 2097152;            //    294,912 f16
    _Float16* wBh    = wAh + 294912;               //    294,912 f16
    _Float16* w1h    = wBh + 294912;               //     65,536 f16
    _Float16* wA0h   = w1h + 65536;                //      9,216 f16
    _Float16* wB0h   = wA0h + 9216;                //      4,096 f16 (adjacent)

    const int B = 16;

    // ---------------- Block 0: Cin=3, Cout=64, 128x128 ----------------
    {
        const int H = 128, W = 128, HW = H * W, npx = B * HW;
        zero_f16_kernel<<<(13312 + 255) / 256, 256, 0, stream>>>(wA0h, 13312);
        prep_w0_kernel<<<64, 64, 0, stream>>>((const float*)d_in[1], wA0h, wB0h);
        xn0_kernel<<<npx / 256, 256, 0, stream>>>(x, xnh, npx, HW);
        init_h_kernel<<<(npx * 64 + 255) / 256, 256, 0, stream>>>(h, S, npx * 64, npx, 64.f);
        for (int it = 0; it < 5; ++it) {
            mfconv3<64, 16, 4, 16, 1, 4, 4, true, false>
                <<<dim3(8, 32, B), 256, 0, stream>>>(h, wA0h, xnh, ratioh, S, nullptr, H, W, 0);
            mf0u_kernel<<<dim3(8, 32, B), 256, 0, stream>>>(ratioh, wB0h, h, S, H, W);
        }
        prep_w1h_kernel<<<16, 256, 0, stream>>>((const float*)d_in[2], w1h, 64 * 64);
        dim3 pg((W / 32) * (H / 2), B);
        posty_kernel<64, 0><<<pg, 256, 0, stream>>>(h, S, w1h, (const float*)d_in[3],
                                                    nullptr, part, nullptr, H, W);
        stats_kernel<64><<<64, 256, 0, stream>>>(part, pg.x * pg.y, 1.0f / (float)npx,
                                                 (const float*)d_in[4], (const float*)d_in[5], bnstats);
        posty_kernel<64, 1><<<pg, 256, 0, stream>>>(h, S, w1h, (const float*)d_in[3],
                                                    bnstats, nullptr, out0h, H, W);
    }

    // ---------------- Block 1: Cin=64, Cout=128, 64x64 ----------------
    {
        const int H = 64, W = 64, HW = H * W, npx = B * HW;
        prep_w_f16_kernel<64, 128><<<128, 256, 0, stream>>>((const float*)d_in[6], wAh, wBh);
        xn12_kernel<64><<<npx / 256, 256, 0, stream>>>(out0h, xnh, npx);
        init_h_kernel<<<(npx * 128 + 255) / 256, 256, 0, stream>>>(h, S, npx * 128, npx, 128.f);
        for (int it = 0; it < 5; ++it) {
            mfconv3<128, 64, 4, 16, 2, 64, 64, true, false>
                <<<dim3(8, 16, B), 256, 0, stream>>>(h, wAh, xnh, ratioh, S, nullptr, H, W, 0);
            mfconv3<64, 128, 4, 16, 2, 128, 128, false, true>
                <<<dim3(8, 16, B), 256, 0, stream>>>(ratioh, wBh, nullptr, h, nullptr, part, H, W, npx);
            combine_S_kernel<2><<<(npx + 255) / 256, 256, 0, stream>>>(part, S, npx);
        }
        prep_w1h_kernel<<<64, 256, 0, stream>>>((const float*)d_in[7], w1h, 128 * 128);
        dim3 pg((W / 32) * (H / 2), B);
        posty_kernel<128, 0><<<pg, 256, 0, stream>>>(h, S, w1h, (const float*)d_in[8],
                                                     nullptr, part, nullptr, H, W);
        stats_kernel<128><<<128, 256, 0, stream>>>(part, pg.x * pg.y, 1.0f / (float)npx,
                                                   (const float*)d_in[9], (const float*)d_in[10], bnstats);
        posty_kernel<128, 1><<<pg, 256, 0, stream>>>(h, S, w1h, (const float*)d_in[8],
                                                     bnstats, nullptr, out1h, H, W);
    }

    // ---------------- Block 2: Cin=128, Cout=256, 32x32 ----------------
    {
        const int H = 32, W = 32, HW = H * W, npx = B * HW;
        prep_w_f16_kernel<128, 256><<<256, 256, 0, stream>>>((const float*)d_in[11], wAh, wBh);
        xn12_kernel<128><<<npx / 256, 256, 0, stream>>>(out1h, xnh, npx);
        init_h_kernel<<<(npx * 256 + 255) / 256, 256, 0, stream>>>(h, S, npx * 256, npx, 256.f);
        for (int it = 0; it < 5; ++it) {
            mfconv3<256, 128, 8, 8, 4, 128, 128, true, false>
                <<<dim3(16, 4, B), 256, 0, stream>>>(h, wAh, xnh, ratioh, S, nullptr, H, W, 0);
            mfconv3<128, 256, 8, 8, 4, 256, 256, false, true>
                <<<dim3(16, 4, B), 256, 0, stream>>>(ratioh, wBh, nullptr, h, nullptr, part, H, W, npx);
            combine_S_kernel<4><<<(npx + 255) / 256, 256, 0, stream>>>(part, S, npx);
        }
        prep_w1h_kernel<<<256, 256, 0, stream>>>((const float*)d_in[12], w1h, 256 * 256);
        dim3 pg((W / 32) * (H / 2), B);
        posty_kernel<256, 0><<<pg, 256, 0, stream>>>(h, S, w1h, (const float*)d_in[13],
                                                     nullptr, part, nullptr, H, W);
        stats_kernel<256><<<256, 256, 0, stream>>>(part, pg.x * pg.y, 1.0f / (float)npx,
                                                   (const float*)d_in[14], (const float*)d_in[15], bnstats);
        posty_kernel<256, 2><<<pg, 256, 0, stream>>>(h, S, w1h, (const float*)d_in[13],
                                                     bnstats, nullptr, d_out, H, W);
    }
}

// Round 9
// 1231.321 us; speedup vs baseline: 1.6768x; 1.6768x over previous
//
#include <hip/hip_runtime.h>

#define EPSV  1e-20f
#define BNEPS 1e-5f

typedef _Float16 f16x8 __attribute__((ext_vector_type(8)));
typedef _Float16 f16x4 __attribute__((ext_vector_type(4)));
typedef float    f32x4 __attribute__((ext_vector_type(4)));

__device__ inline unsigned pack2f16(float a, float b) {
    unsigned short ua = __builtin_bit_cast(unsigned short, (_Float16)a);
    unsigned short ub = __builtin_bit_cast(unsigned short, (_Float16)b);
    return ((unsigned)ub << 16) | ua;
}

// ---------------------------------------------------------------------------
// Weight prep (blocks 1/2): wn = |w|/(sum+eps); chunked GEMM layouts:
//   wBh[kc(ci/32)][tap ][co(COUT)][ci%32]   (update conv: n=co, k=ci)
//   wAh[kc(co/32)][tapf][ci(CIN) ][co%32]   (ratio conv:  n=ci, k=co)
// ---------------------------------------------------------------------------
template<int CIN, int COUT>
__global__ __launch_bounds__(256) void prep_w_f16_kernel(const float* __restrict__ w,
                                                         _Float16* __restrict__ wAh,
                                                         _Float16* __restrict__ wBh)
{
    const int co  = blockIdx.x;
    const int tid = threadIdx.x;
    const int N   = CIN * 9;
    const float* wrow = w + (size_t)co * N;

    float s = 0.f;
    for (int i = tid; i < N; i += 256) s += fabsf(wrow[i]);
    __shared__ float red[4];
    #pragma unroll
    for (int m = 32; m; m >>= 1) s += __shfl_xor(s, m, 64);
    if ((tid & 63) == 0) red[tid >> 6] = s;
    __syncthreads();
    s = red[0] + red[1] + red[2] + red[3];
    const float rn = 1.f / (s + EPSV);

    for (int i = tid; i < N; i += 256) {
        const int ci = i / 9, tap = i % 9;
        const int ky = tap / 3, kx = tap % 3;
        const float v = fabsf(wrow[i]) * rn;
        const int tf = (2 - ky) * 3 + (2 - kx);
        wBh[(((size_t)(ci >> 5) * 9 + tap) * COUT + co) * 32 + (ci & 31)] = (_Float16)v;
        wAh[(((size_t)(co >> 5) * 9 + tf) * CIN + ci) * 32 + (co & 31)] = (_Float16)v;
    }
}

// Block0 weight prep: wB0h[co][tap*4+ci] (K=36 pad 64, im2col update),
//                     wA0h[kc(co/32)][tapf][ci(16)][co%32] (ratio chunks)
__global__ __launch_bounds__(256) void zero_f16_kernel(_Float16* __restrict__ a, int n)
{
    const int i = blockIdx.x * 256 + threadIdx.x;
    if (i < n) a[i] = (_Float16)0.f;
}

__global__ __launch_bounds__(64) void prep_w0_kernel(const float* __restrict__ w,
                                                     _Float16* __restrict__ wA0h,
                                                     _Float16* __restrict__ wB0h)
{
    const int co = blockIdx.x, tid = threadIdx.x;  // 64 threads, 1 wave
    float s = (tid < 27) ? fabsf(w[co * 27 + tid]) : 0.f;
    #pragma unroll
    for (int m = 32; m; m >>= 1) s += __shfl_xor(s, m, 64);
    const float rn = 1.f / (s + EPSV);
    if (tid < 27) {
        const int ci = tid / 9, tap = tid % 9, ky = tap / 3, kx = tap % 3;
        const float v = fabsf(w[co * 27 + tid]) * rn;
        const int tf = (2 - ky) * 3 + (2 - kx);
        wB0h[co * 64 + tap * 4 + ci] = (_Float16)v;
        wA0h[(((co >> 5) * 9 + tf) * 16 + ci) * 32 + (co & 31)] = (_Float16)v;
    }
}

__global__ __launch_bounds__(256) void prep_w1h_kernel(const float* __restrict__ w1,
                                                       _Float16* __restrict__ w1h, int n)
{
    const int i = blockIdx.x * 256 + threadIdx.x;
    if (i < n) w1h[i] = (_Float16)w1[i];
}

// ---------------------------------------------------------------------------
// xn prep.
// ---------------------------------------------------------------------------
__global__ __launch_bounds__(256) void xn0_kernel(const float* __restrict__ x,
                                                  _Float16* __restrict__ xn4,
                                                  int npx, int HW)
{
    const int p = blockIdx.x * 256 + threadIdx.x;
    if (p >= npx) return;
    const int b = p / HW, r = p % HW;
    const float* ip = x + (size_t)b * 3 * HW + r;
    const float v0 = fmaxf(ip[0], 0.f), v1 = fmaxf(ip[HW], 0.f), v2 = fmaxf(ip[2 * HW], 0.f);
    const float rs = 1.f / (v0 + v1 + v2 + EPSV);
    unsigned* d = (unsigned*)(xn4 + (size_t)p * 4);
    d[0] = pack2f16(v0 * rs, v1 * rs);
    d[1] = pack2f16(v2 * rs, 0.f);
}

template<int C>
__global__ __launch_bounds__(256) void xn12_kernel(const _Float16* __restrict__ prev,
                                                   _Float16* __restrict__ xn, int npx)
{
    const int p = blockIdx.x * 256 + threadIdx.x;
    if (p >= npx) return;
    const _Float16* ip = prev + (size_t)p * C;
    _Float16* op = xn + (size_t)p * C;
    f16x8 buf[C / 8];
    float s = 0.f;
    #pragma unroll
    for (int g = 0; g < C / 8; ++g) {
        buf[g] = *(const f16x8*)(ip + g * 8);
        #pragma unroll
        for (int j = 0; j < 8; ++j) {
            float v = fmaxf((float)buf[g][j], 0.f);
            s += v;
            buf[g][j] = (_Float16)v;
        }
    }
    const float rs = 1.f / (s + EPSV);
    #pragma unroll
    for (int g = 0; g < C / 8; ++g) {
        f16x8 o;
        #pragma unroll
        for (int j = 0; j < 8; ++j) o[j] = (_Float16)((float)buf[g][j] * rs);
        *(f16x8*)(op + g * 8) = o;
    }
}

__global__ __launch_bounds__(256) void init_h_kernel(_Float16* __restrict__ h, float* __restrict__ S,
                                                     int nh, int ns, float cval)
{
    const int i = blockIdx.x * 256 + threadIdx.x;
    if (i < nh) h[i] = (_Float16)1.f;
    if (i < ns) S[i] = cval;
}

template<int NS>
__global__ __launch_bounds__(256) void combine_S_kernel(const float* __restrict__ sp,
                                                        float* __restrict__ S, int npx)
{
    const int i = blockIdx.x * 256 + threadIdx.x;
    if (i >= npx) return;
    float s = sp[i];
    #pragma unroll
    for (int k = 1; k < NS; ++k) s += sp[(size_t)k * npx + i];
    S[i] = s;
}

// ---------------------------------------------------------------------------
// mfconv4: NHWC f16 MFMA implicit-GEMM 3x3 conv; per-32k chunks with BOTH
//   input and weights double-buffered in LDS, bulk-prefetched one chunk
//   ahead (one barrier per chunk). MFMA path reads ONLY LDS.
//   Weights global layout: [kc][tap][n(OCg)][32]; LDS [tap][OCWG][40].
//   NORM_IN: input scaled by 1/(Sin+eps) while staging (ratio conv, in=h).
//   !UPDATE: out = aux/(acc+eps) f16, stride OST, only oc<NW written.
//   UPDATE : h f16 RMW (*= acc), S partials at split*sstride.
// ---------------------------------------------------------------------------
template<int ICg, int OCg, int TH, int TW, int NSPLIT, int OST, int NW,
         bool NORM_IN, bool UPDATE>
__global__ __launch_bounds__(256) void mfconv4(
    const _Float16* __restrict__ in, const _Float16* __restrict__ wgt,
    const _Float16* __restrict__ aux, _Float16* __restrict__ out,
    const float* __restrict__ Sin, float* __restrict__ Sout,
    int H, int W, int sstride)
{
    constexpr int OCWG = OCg / NSPLIT;
    constexpr int NF = OCWG / 16;
    constexpr int HS = TH + 2, WSp = TW + 2, NSP = HS * WSp;
    constexpr int ICP = 40;                 // 32 + 8 pad (16B aligned rows)
    constexpr int NCH = ICg / 32;
    constexpr int LS = (NSPLIT == 8) ? 3 : (NSPLIT == 4) ? 2 : (NSPLIT == 2) ? 1 : 0;
    constexpr int NLD = NSP * 4;            // input f16x8 loads per chunk
    constexpr int IREG = (NLD + 255) / 256;
    constexpr int WOC = OCWG * 40;          // padded per-tap w block (f16)
    constexpr int NWLD = 9 * OCWG * 4;      // weight f16x8 loads per chunk
    constexpr int WREG = (NWLD + 255) / 256;
    static_assert(TH * TW == 64 && OCWG % 16 == 0 && ICg % 32 == 0, "cfg");

    __shared__ _Float16 in_t[2][NSP * ICP];
    __shared__ _Float16 w_t[2][9 * WOC];
    __shared__ float rS[NORM_IN ? NSP : 1];

    const int tid = threadIdx.x;
    const int lane = tid & 63, wave = tid >> 6;
    const int kq = lane >> 4, l15 = lane & 15;
    const int split = blockIdx.x & (NSPLIT - 1);
    const int tx = blockIdx.x >> LS;
    const int x0 = tx * TW, y0 = blockIdx.y * TH, b = blockIdx.z;
    const int HW = H * W;
    const int oc0 = split * OCWG;

    f16x8 ild[IREG];
    f16x8 wld[WREG];

    auto iload = [&](int kc) {
        #pragma unroll
        for (int r = 0; r < IREG; ++r) {
            const int i = tid + r * 256;
            f16x8 v = {0, 0, 0, 0, 0, 0, 0, 0};
            if (i < NLD) {
                const int sp = i >> 2, seg = i & 3;
                const int yy = y0 + sp / WSp - 1, xx = x0 + sp % WSp - 1;
                if (yy >= 0 && yy < H && xx >= 0 && xx < W)
                    v = __builtin_nontemporal_load((const f16x8*)(in +
                        ((size_t)b * HW + (size_t)yy * W + xx) * ICg + kc * 32 + seg * 8));
            }
            ild[r] = v;
        }
    };
    auto wload = [&](int kc) {
        #pragma unroll
        for (int r = 0; r < WREG; ++r) {
            const int j = tid + r * 256;
            if (j < NWLD) {
                const int tap = j / (OCWG * 4), rem = j % (OCWG * 4);
                const int oc = rem >> 2, e = rem & 3;
                wld[r] = *(const f16x8*)(wgt +
                    (((size_t)kc * 9 + tap) * OCg + oc0 + oc) * 32 + e * 8);
            }
        }
    };
    auto iwrite = [&](int buf) {
        #pragma unroll
        for (int r = 0; r < IREG; ++r) {
            const int i = tid + r * 256;
            if (i < NLD) {
                const int sp = i >> 2, seg = i & 3;
                if constexpr (NORM_IN) {
                    const float f = rS[sp];
                    unsigned* d = (unsigned*)&in_t[buf][sp * ICP + seg * 8];
                    d[0] = pack2f16((float)ild[r][0] * f, (float)ild[r][1] * f);
                    d[1] = pack2f16((float)ild[r][2] * f, (float)ild[r][3] * f);
                    d[2] = pack2f16((float)ild[r][4] * f, (float)ild[r][5] * f);
                    d[3] = pack2f16((float)ild[r][6] * f, (float)ild[r][7] * f);
                } else {
                    *(f16x8*)&in_t[buf][sp * ICP + seg * 8] = ild[r];
                }
            }
        }
    };
    auto wwrite = [&](int buf) {
        #pragma unroll
        for (int r = 0; r < WREG; ++r) {
            const int j = tid + r * 256;
            if (j < NWLD) {
                const int tap = j / (OCWG * 4), rem = j % (OCWG * 4);
                const int oc = rem >> 2, e = rem & 3;
                *(f16x8*)&w_t[buf][tap * WOC + oc * 40 + e * 8] = wld[r];
            }
        }
    };

    const int m = wave * 16 + l15;
    const int pyl = m / TW, pxl = m % TW;

    f32x4 acc[NF];
    #pragma unroll
    for (int nf = 0; nf < NF; ++nf) acc[nf] = (f32x4){0.f, 0.f, 0.f, 0.f};

    // prologue
    iload(0); wload(0);
    if constexpr (NORM_IN) {
        for (int i = tid; i < NSP; i += 256) {
            const int yy = y0 + i / WSp - 1, xx = x0 + i % WSp - 1;
            float sv = 0.f;
            if (yy >= 0 && yy < H && xx >= 0 && xx < W)
                sv = Sin[(size_t)b * HW + (size_t)yy * W + xx];
            rS[i] = 1.f / (sv + EPSV);
        }
        __syncthreads();
    }
    iwrite(0); wwrite(0);
    __syncthreads();

    int cur = 0;
    for (int kc = 0; kc < NCH; ++kc) {
        if (kc + 1 < NCH) { iload(kc + 1); wload(kc + 1); }
        // ---- compute chunk from LDS only ----
        {
            const _Float16* ib = &in_t[cur][0] + (pyl * WSp + pxl) * ICP + kq * 8;
            const _Float16* wb = &w_t[cur][0] + l15 * 40 + kq * 8;
            #pragma unroll
            for (int dy = 0; dy < 3; ++dy) {
                #pragma unroll
                for (int dx = 0; dx < 3; ++dx) {
                    const int tap = dy * 3 + dx;
                    const f16x8 afr = *(const f16x8*)(ib + (dy * WSp + dx) * ICP);
                    #pragma unroll
                    for (int nf = 0; nf < NF; ++nf) {
                        const f16x8 bfr = *(const f16x8*)(wb + tap * WOC + nf * 16 * 40);
                        acc[nf] = __builtin_amdgcn_mfma_f32_16x16x32_f16(afr, bfr, acc[nf], 0, 0, 0);
                    }
                }
            }
        }
        if (kc + 1 < NCH) {
            iwrite(cur ^ 1); wwrite(cur ^ 1);
            __syncthreads();
            cur ^= 1;
        }
    }

    // ---- epilogue ----
    const int pl = wave * 16 + kq * 4;
    const int py0 = pl / TW, px0 = pl % TW;
    const size_t pixbase = (size_t)b * HW + (size_t)(y0 + py0) * W + x0 + px0;

    if constexpr (!UPDATE) {
        #pragma unroll
        for (int nf = 0; nf < NF; ++nf) {
            const int oc = oc0 + nf * 16 + l15;
            if (oc < NW) {
                #pragma unroll
                for (int r = 0; r < 4; ++r) {
                    const size_t idx = (pixbase + r) * OST + oc;
                    out[idx] = (_Float16)((float)aux[idx] / (acc[nf][r] + EPSV));
                }
            }
        }
    } else {
        float s[4] = {0.f, 0.f, 0.f, 0.f};
        #pragma unroll
        for (int nf = 0; nf < NF; ++nf) {
            const int oc = oc0 + nf * 16 + l15;
            #pragma unroll
            for (int r = 0; r < 4; ++r) {
                const size_t idx = (pixbase + r) * OST + oc;
                const float hv = (float)out[idx] * acc[nf][r];
                const _Float16 hq = (_Float16)hv;
                out[idx] = hq;
                s[r] += (float)hq;
            }
        }
        #pragma unroll
        for (int mm = 1; mm < 16; mm <<= 1) {
            #pragma unroll
            for (int r = 0; r < 4; ++r) s[r] += __shfl_xor(s[r], mm);
        }
        if (l15 == 0) {
            float* sp_ = Sout + (size_t)split * sstride + pixbase;
            sp_[0] = s[0]; sp_[1] = s[1]; sp_[2] = s[2]; sp_[3] = s[3];
        }
    }
}

// ---------------------------------------------------------------------------
// Block0 update conv (3 -> 64) via im2col MFMA, h f16 RMW.
// ---------------------------------------------------------------------------
__global__ __launch_bounds__(256) void mf0u_kernel(
    const _Float16* __restrict__ ratio4, const _Float16* __restrict__ wB0h,
    _Float16* __restrict__ h, float* __restrict__ Sout, int H, int W)
{
    constexpr int TW = 16;
    __shared__ _Float16 a_t[64 * 72];

    const int tid = threadIdx.x;
    const int lane = tid & 63, wave = tid >> 6;
    const int kq = lane >> 4, l15 = lane & 15;
    const int x0 = blockIdx.x * TW, y0 = blockIdx.y * 4, b = blockIdx.z;
    const int HW = H * W;

    for (int i = tid; i < 64 * 72 / 2; i += 256) ((unsigned*)a_t)[i] = 0;
    __syncthreads();
    for (int i = tid; i < 576; i += 256) {
        const int px = i / 9, tap = i % 9;
        const int py = px / TW, pxx = px % TW;
        const int yy = y0 + py + tap / 3 - 1, xx = x0 + pxx + tap % 3 - 1;
        if (yy >= 0 && yy < H && xx >= 0 && xx < W)
            *(f16x4*)&a_t[px * 72 + tap * 4] =
                *(const f16x4*)(ratio4 + ((size_t)b * HW + (size_t)yy * W + xx) * 4);
    }
    __syncthreads();

    f32x4 acc[4];
    #pragma unroll
    for (int nf = 0; nf < 4; ++nf) acc[nf] = (f32x4){0.f, 0.f, 0.f, 0.f};
    #pragma unroll
    for (int kc = 0; kc < 2; ++kc) {
        const f16x8 afr = *(const f16x8*)&a_t[(wave * 16 + l15) * 72 + kc * 32 + kq * 8];
        #pragma unroll
        for (int nf = 0; nf < 4; ++nf) {
            const f16x8 bfr = *(const f16x8*)(wB0h + (size_t)(nf * 16 + l15) * 64 + kc * 32 + kq * 8);
            acc[nf] = __builtin_amdgcn_mfma_f32_16x16x32_f16(afr, bfr, acc[nf], 0, 0, 0);
        }
    }

    const int pl = wave * 16 + kq * 4;
    const size_t pixbase = (size_t)b * HW + (size_t)(y0 + pl / TW) * W + x0 + pl % TW;
    float s[4] = {0.f, 0.f, 0.f, 0.f};
    #pragma unroll
    for (int nf = 0; nf < 4; ++nf) {
        const int oc = nf * 16 + l15;
        #pragma unroll
        for (int r = 0; r < 4; ++r) {
            const size_t idx = (pixbase + r) * 64 + oc;
            const float hv = (float)h[idx] * acc[nf][r];
            const _Float16 hq = (_Float16)hv;
            h[idx] = hq;
            s[r] += (float)hq;
        }
    }
    #pragma unroll
    for (int mm = 1; mm < 16; mm <<= 1) {
        #pragma unroll
        for (int r = 0; r < 4; ++r) s[r] += __shfl_xor(s[r], mm);
    }
    if (l15 == 0) {
        float* sp_ = Sout + pixbase;
        sp_[0] = s[0]; sp_[1] = s[1]; sp_[2] = s[2]; sp_[3] = s[3];
    }
}

// ---------------------------------------------------------------------------
// posty (MFMA 1x1 conv), two-pass; h f16. Tile = 2 rows x 32 cols.
//   MODE 0: stats partials. MODE 1: pool+BN -> f16 NHWC. MODE 2: fp32 NCHW.
// ---------------------------------------------------------------------------
template<int C, int MODE>
__global__ __launch_bounds__(256) void posty_kernel(
    const _Float16* __restrict__ h, const float* __restrict__ S,
    const _Float16* __restrict__ w1h, const float* __restrict__ bias,
    const float* __restrict__ bnst, float* __restrict__ part,
    void* __restrict__ outp, int H, int W)
{
    constexpr int NF = C / 16, CP = C + 8;
    __shared__ _Float16 a_t[64 * CP];
    __shared__ float rs_t[64];
    __shared__ float sred1[MODE == 0 ? 4 * C : 1];
    __shared__ float sred2[MODE == 0 ? 4 * C : 1];

    const int tid = threadIdx.x;
    const int lane = tid & 63, wave = tid >> 6;
    const int kq = lane >> 4, l15 = lane & 15;
    const int WT = W / 32;
    const int tx = blockIdx.x % WT, ty = blockIdx.x / WT;
    const int b = blockIdx.y;
    const int HW = H * W;

    if (tid < 64) {
        const int gp = (2 * ty + (tid >> 5)) * W + tx * 32 + (tid & 31);
        rs_t[tid] = 1.f / (S[(size_t)b * HW + gp] + EPSV);
    }
    __syncthreads();
    for (int i = tid; i < 64 * (C / 8); i += 256) {
        const int sp = i / (C / 8), seg = i % (C / 8);
        const int gp = (2 * ty + (sp >> 5)) * W + tx * 32 + (sp & 31);
        const f16x8 v = *(const f16x8*)(h + ((size_t)b * HW + gp) * C + seg * 8);
        const float f = rs_t[sp];
        unsigned* d = (unsigned*)&a_t[sp * CP + seg * 8];
        d[0] = pack2f16((float)v[0] * f, (float)v[1] * f);
        d[1] = pack2f16((float)v[2] * f, (float)v[3] * f);
        d[2] = pack2f16((float)v[4] * f, (float)v[5] * f);
        d[3] = pack2f16((float)v[6] * f, (float)v[7] * f);
    }
    __syncthreads();

    f32x4 acc[NF];
    #pragma unroll
    for (int nf = 0; nf < NF; ++nf) acc[nf] = (f32x4){0.f, 0.f, 0.f, 0.f};
    #pragma unroll
    for (int kc = 0; kc < C / 32; ++kc) {
        const f16x8 afr = *(const f16x8*)&a_t[(wave * 16 + l15) * CP + kc * 32 + kq * 8];
        #pragma unroll
        for (int nf = 0; nf < NF; ++nf) {
            const f16x8 bfr = *(const f16x8*)(w1h + (size_t)(nf * 16 + l15) * C + kc * 32 + kq * 8);
            acc[nf] = __builtin_amdgcn_mfma_f32_16x16x32_f16(afr, bfr, acc[nf], 0, 0, 0);
        }
    }

    const int pl = wave * 16 + kq * 4;

    if constexpr (MODE == 0) {
        const int wgid = b * gridDim.x + blockIdx.x;
        #pragma unroll
        for (int nf = 0; nf < NF; ++nf) {
            const int oc = nf * 16 + l15;
            const float bv = bias[oc];
            float s1 = 0.f, s2 = 0.f;
            #pragma unroll
            for (int r = 0; r < 4; ++r) {
                const float y = fmaxf(acc[nf][r] + bv, 0.f);
                s1 += y; s2 += y * y;
            }
            s1 += __shfl_xor(s1, 16); s2 += __shfl_xor(s2, 16);
            s1 += __shfl_xor(s1, 32); s2 += __shfl_xor(s2, 32);
            if (kq == 0) {
                sred1[wave * C + oc] = s1;
                sred2[wave * C + oc] = s2;
            }
        }
        __syncthreads();
        for (int oc = tid; oc < C; oc += 256) {
            const float s1 = sred1[oc] + sred1[C + oc] + sred1[2 * C + oc] + sred1[3 * C + oc];
            const float s2 = sred2[oc] + sred2[C + oc] + sred2[2 * C + oc] + sred2[3 * C + oc];
            part[((size_t)wgid * C + oc) * 2 + 0] = s1;
            part[((size_t)wgid * C + oc) * 2 + 1] = s2;
        }
    } else {
        __syncthreads();        // all A-reads complete; reuse a_t for Y
        #pragma unroll
        for (int nf = 0; nf < NF; ++nf) {
            const int oc = nf * 16 + l15;
            const float bv = bias[oc];
            #pragma unroll
            for (int r = 0; r < 4; ++r)
                a_t[(pl + r) * CP + oc] = (_Float16)fmaxf(acc[nf][r] + bv, 0.f);
        }
        __syncthreads();
        const int Wo = W >> 1;
        for (int i = tid; i < 16 * C; i += 256) {
            int ox, c;
            if constexpr (MODE == 1) { c = i % C; ox = i / C; }
            else                     { ox = i % 16; c = i / 16; }
            const float y00 = (float)a_t[(2 * ox) * CP + c];
            const float y01 = (float)a_t[(2 * ox + 1) * CP + c];
            const float y10 = (float)a_t[(32 + 2 * ox) * CP + c];
            const float y11 = (float)a_t[(32 + 2 * ox + 1) * CP + c];
            const float v = (y00 + y01 + y10 + y11) * 0.25f * bnst[c] + bnst[C + c];
            if constexpr (MODE == 1) {
                ((_Float16*)outp)[((size_t)b * (HW >> 2) + (size_t)ty * Wo + tx * 16 + ox) * C + c] =
                    (_Float16)v;
            } else {
                ((float*)outp)[(((size_t)b * C + c) * (size_t)(H >> 1) + ty) * Wo + tx * 16 + ox] = v;
            }
        }
    }
}

// Reduce partials -> per-channel (scale, shift) for BN affine.
template<int C>
__global__ __launch_bounds__(256) void stats_kernel(const float* __restrict__ part, int nwg, float invM,
                                                    const float* __restrict__ gamma,
                                                    const float* __restrict__ beta,
                                                    float* __restrict__ stats)
{
    const int oc = blockIdx.x;
    const int tid = threadIdx.x;
    float s1 = 0.f, s2 = 0.f;
    for (int w = tid; w < nwg; w += 256) {
        s1 += part[((size_t)w * C + oc) * 2 + 0];
        s2 += part[((size_t)w * C + oc) * 2 + 1];
    }
    __shared__ float r1[4], r2[4];
    #pragma unroll
    for (int m = 32; m; m >>= 1) { s1 += __shfl_xor(s1, m, 64); s2 += __shfl_xor(s2, m, 64); }
    if ((tid & 63) == 0) { r1[tid >> 6] = s1; r2[tid >> 6] = s2; }
    __syncthreads();
    if (tid == 0) {
        s1 = r1[0] + r1[1] + r1[2] + r1[3];
        s2 = r2[0] + r2[1] + r2[2] + r2[3];
        const float mean = s1 * invM;
        const float var  = s2 * invM - mean * mean;
        const float rstd = rsqrtf(var + BNEPS);
        const float scale = gamma[oc] * rstd;
        stats[oc]     = scale;
        stats[C + oc] = beta[oc] - mean * scale;
    }
}

// ---------------------------------------------------------------------------
extern "C" void kernel_launch(void* const* d_in, const int* in_sizes, int n_in,
                              void* d_out, int out_size, void* d_ws, size_t ws_size,
                              hipStream_t stream)
{
    const float* x = (const float*)d_in[0];
    float* ws      = (float*)d_ws;
    float* S       = ws;                    //    262,144 f32
    float* part    = S + 262144;            //  1,048,576 f32
    float* bnstats = part + 1048576;        //        512 f32
    _Float16* h      = (_Float16*)(bnstats + 512); // 16,777,216 f16
    _Float16* xnh    = h + 16777216;               //  4,194,304 f16
    _Float16* ratioh = xnh + 4194304;              //  4,194,304 f16
    _Float16* out0h  = ratioh + 4194304;           //  4,194,304 f16
    _Float16* out1h  = out0h + 4194304;            //  2,097,152 f16
    _Float16* wAh    = out1h + 2097152;            //    294,912 f16
    _Float16* wBh    = wAh + 294912;               //    294,912 f16
    _Float16* w1h    = wBh + 294912;               //     65,536 f16
    _Float16* wA0h   = w1h + 65536;                //      9,216 f16
    _Float16* wB0h   = wA0h + 9216;                //      4,096 f16 (adjacent)

    const int B = 16;

    // ---------------- Block 0: Cin=3, Cout=64, 128x128 ----------------
    {
        const int H = 128, W = 128, HW = H * W, npx = B * HW;
        zero_f16_kernel<<<(9216 + 255) / 256, 256, 0, stream>>>(wA0h, 9216);
        prep_w0_kernel<<<64, 64, 0, stream>>>((const float*)d_in[1], wA0h, wB0h);
        xn0_kernel<<<npx / 256, 256, 0, stream>>>(x, xnh, npx, HW);
        init_h_kernel<<<(npx * 64 + 255) / 256, 256, 0, stream>>>(h, S, npx * 64, npx, 64.f);
        for (int it = 0; it < 5; ++it) {
            mfconv4<64, 16, 4, 16, 1, 4, 4, true, false>
                <<<dim3(8, 32, B), 256, 0, stream>>>(h, wA0h, xnh, ratioh, S, nullptr, H, W, 0);
            mf0u_kernel<<<dim3(8, 32, B), 256, 0, stream>>>(ratioh, wB0h, h, S, H, W);
        }
        prep_w1h_kernel<<<16, 256, 0, stream>>>((const float*)d_in[2], w1h, 64 * 64);
        dim3 pg((W / 32) * (H / 2), B);
        posty_kernel<64, 0><<<pg, 256, 0, stream>>>(h, S, w1h, (const float*)d_in[3],
                                                    nullptr, part, nullptr, H, W);
        stats_kernel<64><<<64, 256, 0, stream>>>(part, pg.x * pg.y, 1.0f / (float)npx,
                                                 (const float*)d_in[4], (const float*)d_in[5], bnstats);
        posty_kernel<64, 1><<<pg, 256, 0, stream>>>(h, S, w1h, (const float*)d_in[3],
                                                    bnstats, nullptr, out0h, H, W);
    }

    // ---------------- Block 1: Cin=64, Cout=128, 64x64 ----------------
    {
        const int H = 64, W = 64, HW = H * W, npx = B * HW;
        prep_w_f16_kernel<64, 128><<<128, 256, 0, stream>>>((const float*)d_in[6], wAh, wBh);
        xn12_kernel<64><<<npx / 256, 256, 0, stream>>>(out0h, xnh, npx);
        init_h_kernel<<<(npx * 128 + 255) / 256, 256, 0, stream>>>(h, S, npx * 128, npx, 128.f);
        for (int it = 0; it < 5; ++it) {
            mfconv4<128, 64, 4, 16, 2, 64, 64, true, false>
                <<<dim3(8, 16, B), 256, 0, stream>>>(h, wAh, xnh, ratioh, S, nullptr, H, W, 0);
            mfconv4<64, 128, 4, 16, 4, 128, 128, false, true>
                <<<dim3(16, 16, B), 256, 0, stream>>>(ratioh, wBh, nullptr, h, nullptr, part, H, W, npx);
            combine_S_kernel<4><<<(npx + 255) / 256, 256, 0, stream>>>(part, S, npx);
        }
        prep_w1h_kernel<<<64, 256, 0, stream>>>((const float*)d_in[7], w1h, 128 * 128);
        dim3 pg((W / 32) * (H / 2), B);
        posty_kernel<128, 0><<<pg, 256, 0, stream>>>(h, S, w1h, (const float*)d_in[8],
                                                     nullptr, part, nullptr, H, W);
        stats_kernel<128><<<128, 256, 0, stream>>>(part, pg.x * pg.y, 1.0f / (float)npx,
                                                   (const float*)d_in[9], (const float*)d_in[10], bnstats);
        posty_kernel<128, 1><<<pg, 256, 0, stream>>>(h, S, w1h, (const float*)d_in[8],
                                                     bnstats, nullptr, out1h, H, W);
    }

    // ---------------- Block 2: Cin=128, Cout=256, 32x32 ----------------
    {
        const int H = 32, W = 32, HW = H * W, npx = B * HW;
        prep_w_f16_kernel<128, 256><<<256, 256, 0, stream>>>((const float*)d_in[11], wAh, wBh);
        xn12_kernel<128><<<npx / 256, 256, 0, stream>>>(out1h, xnh, npx);
        init_h_kernel<<<(npx * 256 + 255) / 256, 256, 0, stream>>>(h, S, npx * 256, npx, 256.f);
        for (int it = 0; it < 5; ++it) {
            mfconv4<256, 128, 8, 8, 4, 128, 128, true, false>
                <<<dim3(16, 4, B), 256, 0, stream>>>(h, wAh, xnh, ratioh, S, nullptr, H, W, 0);
            mfconv4<128, 256, 8, 8, 8, 256, 256, false, true>
                <<<dim3(32, 4, B), 256, 0, stream>>>(ratioh, wBh, nullptr, h, nullptr, part, H, W, npx);
            combine_S_kernel<8><<<(npx + 255) / 256, 256, 0, stream>>>(part, S, npx);
        }
        prep_w1h_kernel<<<256, 256, 0, stream>>>((const float*)d_in[12], w1h, 256 * 256);
        dim3 pg((W / 32) * (H / 2), B);
        posty_kernel<256, 0><<<pg, 256, 0, stream>>>(h, S, w1h, (const float*)d_in[13],
                                                     nullptr, part, nullptr, H, W);
        stats_kernel<256><<<256, 256, 0, stream>>>(part, pg.x * pg.y, 1.0f / (float)npx,
                                                   (const float*)d_in[14], (const float*)d_in[15], bnstats);
        posty_kernel<256, 2><<<pg, 256, 0, stream>>>(h, S, w1h, (const float*)d_in[13],
                                                     bnstats, nullptr, d_out, H, W);
    }
}

// Round 10
// 958.642 us; speedup vs baseline: 2.1537x; 1.2844x over previous
//
#include <hip/hip_runtime.h>

#define EPSV  1e-20f
#define BNEPS 1e-5f

typedef _Float16 f16x8 __attribute__((ext_vector_type(8)));
typedef _Float16 f16x4 __attribute__((ext_vector_type(4)));
typedef float    f32x4 __attribute__((ext_vector_type(4)));

__device__ inline unsigned pack2f16(float a, float b) {
    unsigned short ua = __builtin_bit_cast(unsigned short, (_Float16)a);
    unsigned short ub = __builtin_bit_cast(unsigned short, (_Float16)b);
    return ((unsigned)ub << 16) | ua;
}

// ---------------------------------------------------------------------------
// Weight prep (blocks 1/2): wn = |w|/(sum+eps); chunked GEMM layouts:
//   wBh[kc(ci/32)][tap ][co(COUT)][ci%32]   (update conv: n=co, k=ci)
//   wAh[kc(co/32)][tapf][ci(CIN) ][co%32]   (ratio conv:  n=ci, k=co)
// ---------------------------------------------------------------------------
template<int CIN, int COUT>
__global__ __launch_bounds__(256) void prep_w_f16_kernel(const float* __restrict__ w,
                                                         _Float16* __restrict__ wAh,
                                                         _Float16* __restrict__ wBh)
{
    const int co  = blockIdx.x;
    const int tid = threadIdx.x;
    const int N   = CIN * 9;
    const float* wrow = w + (size_t)co * N;

    float s = 0.f;
    for (int i = tid; i < N; i += 256) s += fabsf(wrow[i]);
    __shared__ float red[4];
    #pragma unroll
    for (int m = 32; m; m >>= 1) s += __shfl_xor(s, m, 64);
    if ((tid & 63) == 0) red[tid >> 6] = s;
    __syncthreads();
    s = red[0] + red[1] + red[2] + red[3];
    const float rn = 1.f / (s + EPSV);

    for (int i = tid; i < N; i += 256) {
        const int ci = i / 9, tap = i % 9;
        const int ky = tap / 3, kx = tap % 3;
        const float v = fabsf(wrow[i]) * rn;
        const int tf = (2 - ky) * 3 + (2 - kx);
        wBh[(((size_t)(ci >> 5) * 9 + tap) * COUT + co) * 32 + (ci & 31)] = (_Float16)v;
        wAh[(((size_t)(co >> 5) * 9 + tf) * CIN + ci) * 32 + (co & 31)] = (_Float16)v;
    }
}

// Block0 weight prep: wB0h[co][tap*4+ci] (K=36 pad 64, im2col update),
//                     wA0h[kc(co/32)][tapf][ci(16)][co%32] (ratio chunks)
__global__ __launch_bounds__(256) void zero_f16_kernel(_Float16* __restrict__ a, int n)
{
    const int i = blockIdx.x * 256 + threadIdx.x;
    if (i < n) a[i] = (_Float16)0.f;
}

__global__ __launch_bounds__(64) void prep_w0_kernel(const float* __restrict__ w,
                                                     _Float16* __restrict__ wA0h,
                                                     _Float16* __restrict__ wB0h)
{
    const int co = blockIdx.x, tid = threadIdx.x;  // 64 threads, 1 wave
    float s = (tid < 27) ? fabsf(w[co * 27 + tid]) : 0.f;
    #pragma unroll
    for (int m = 32; m; m >>= 1) s += __shfl_xor(s, m, 64);
    const float rn = 1.f / (s + EPSV);
    if (tid < 27) {
        const int ci = tid / 9, tap = tid % 9, ky = tap / 3, kx = tap % 3;
        const float v = fabsf(w[co * 27 + tid]) * rn;
        const int tf = (2 - ky) * 3 + (2 - kx);
        wB0h[co * 64 + tap * 4 + ci] = (_Float16)v;
        wA0h[(((co >> 5) * 9 + tf) * 16 + ci) * 32 + (co & 31)] = (_Float16)v;
    }
}

__global__ __launch_bounds__(256) void prep_w1h_kernel(const float* __restrict__ w1,
                                                       _Float16* __restrict__ w1h, int n)
{
    const int i = blockIdx.x * 256 + threadIdx.x;
    if (i < n) w1h[i] = (_Float16)w1[i];
}

// ---------------------------------------------------------------------------
// xn prep.
// ---------------------------------------------------------------------------
__global__ __launch_bounds__(256) void xn0_kernel(const float* __restrict__ x,
                                                  _Float16* __restrict__ xn4,
                                                  int npx, int HW)
{
    const int p = blockIdx.x * 256 + threadIdx.x;
    if (p >= npx) return;
    const int b = p / HW, r = p % HW;
    const float* ip = x + (size_t)b * 3 * HW + r;
    const float v0 = fmaxf(ip[0], 0.f), v1 = fmaxf(ip[HW], 0.f), v2 = fmaxf(ip[2 * HW], 0.f);
    const float rs = 1.f / (v0 + v1 + v2 + EPSV);
    unsigned* d = (unsigned*)(xn4 + (size_t)p * 4);
    d[0] = pack2f16(v0 * rs, v1 * rs);
    d[1] = pack2f16(v2 * rs, 0.f);
}

template<int C>
__global__ __launch_bounds__(256) void xn12_kernel(const _Float16* __restrict__ prev,
                                                   _Float16* __restrict__ xn, int npx)
{
    const int p = blockIdx.x * 256 + threadIdx.x;
    if (p >= npx) return;
    const _Float16* ip = prev + (size_t)p * C;
    _Float16* op = xn + (size_t)p * C;
    f16x8 buf[C / 8];
    float s = 0.f;
    #pragma unroll
    for (int g = 0; g < C / 8; ++g) {
        buf[g] = *(const f16x8*)(ip + g * 8);
        #pragma unroll
        for (int j = 0; j < 8; ++j) {
            float v = fmaxf((float)buf[g][j], 0.f);
            s += v;
            buf[g][j] = (_Float16)v;
        }
    }
    const float rs = 1.f / (s + EPSV);
    #pragma unroll
    for (int g = 0; g < C / 8; ++g) {
        f16x8 o;
        #pragma unroll
        for (int j = 0; j < 8; ++j) o[j] = (_Float16)((float)buf[g][j] * rs);
        *(f16x8*)(op + g * 8) = o;
    }
}

__global__ __launch_bounds__(256) void init_h_kernel(_Float16* __restrict__ h, float* __restrict__ S,
                                                     int nh, int ns, float cval)
{
    const int i = blockIdx.x * 256 + threadIdx.x;
    if (i < nh) h[i] = (_Float16)1.f;
    if (i < ns) S[i] = cval;
}

template<int NS>
__global__ __launch_bounds__(256) void combine_S_kernel(const float* __restrict__ sp,
                                                        float* __restrict__ S, int npx)
{
    const int i = blockIdx.x * 256 + threadIdx.x;
    if (i >= npx) return;
    float s = sp[i];
    #pragma unroll
    for (int k = 1; k < NS; ++k) s += sp[(size_t)k * npx + i];
    S[i] = s;
}

// ---------------------------------------------------------------------------
// mfconv5: NHWC f16 MFMA implicit-GEMM 3x3 conv, high-reuse register tiling.
//   Tile = 16x16 px, 4 waves; wave owns 4 M-frags (64 px) x NF oc-frags.
//   Per-32k chunks, input+weights double-buffered in LDS (one barrier/chunk);
//   MFMA path reads ONLY LDS; reads/MFMA = (4+NF)/(4*NF).
//   Input LDS [sp][40] (2-way max); weights LDS [tap][oc][32] with XOR slot
//   swizzle slot = kq ^ ((oc>>1)&3) -> conflict-free reads/writes.
//   NORM_IN: input scaled by 1/(Sin+eps) while staging (ratio conv, in=h).
//   !UPDATE: out = aux/(acc+eps) f16, stride OST, only oc<NW written.
//   UPDATE : h f16 RMW (*= acc), S partials at split*sstride.
// Weights global: [kc][tap][n(OCg)][32].
// ---------------------------------------------------------------------------
template<int ICg, int OCg, int NSPLIT, int OST, int NW, bool NORM_IN, bool UPDATE>
__global__ __launch_bounds__(256, 1) void mfconv5(
    const _Float16* __restrict__ in, const _Float16* __restrict__ wgt,
    const _Float16* __restrict__ aux, _Float16* __restrict__ out,
    const float* __restrict__ Sin, float* __restrict__ Sout,
    int H, int W, int sstride)
{
    constexpr int OCWG = OCg / NSPLIT;
    constexpr int NF = OCWG / 16;
    constexpr int HS = 18, WSp = 18, NSP = HS * WSp;   // 16x16 tile + halo
    constexpr int ICP = 40;
    constexpr int NCH = ICg / 32;
    constexpr int LS = (NSPLIT == 4) ? 2 : (NSPLIT == 2) ? 1 : 0;
    constexpr int NLD = NSP * 4;                        // input f16x8 loads/chunk
    constexpr int IREG = (NLD + 255) / 256;             // 6
    constexpr int WOC = OCWG * 32;                      // f16 per tap block
    constexpr int NWLD = 9 * OCWG * 4;                  // weight f16x8 loads/chunk
    constexpr int WREG = (NWLD + 255) / 256;
    static_assert(OCWG % 16 == 0 && ICg % 32 == 0, "cfg");

    __shared__ _Float16 in_t[2][NSP * ICP];
    __shared__ _Float16 w_t[2][9 * WOC];
    __shared__ float rS[NORM_IN ? NSP : 1];

    const int tid = threadIdx.x;
    const int lane = tid & 63, wave = tid >> 6;
    const int kq = lane >> 4, l15 = lane & 15;
    const int split = blockIdx.x & (NSPLIT - 1);
    const int tx = blockIdx.x >> LS;
    const int x0 = tx * 16, y0 = blockIdx.y * 16, b = blockIdx.z;
    const int HW = H * W;
    const int oc0 = split * OCWG;

    f16x8 ild[IREG];
    f16x8 wld[WREG];

    auto iload = [&](int kc) {
        #pragma unroll
        for (int r = 0; r < IREG; ++r) {
            const int i = tid + r * 256;
            f16x8 v = {0, 0, 0, 0, 0, 0, 0, 0};
            if (i < NLD) {
                const int sp = i >> 2, seg = i & 3;
                const int yy = y0 + sp / WSp - 1, xx = x0 + sp % WSp - 1;
                if (yy >= 0 && yy < H && xx >= 0 && xx < W)
                    v = __builtin_nontemporal_load((const f16x8*)(in +
                        ((size_t)b * HW + (size_t)yy * W + xx) * ICg + kc * 32 + seg * 8));
            }
            ild[r] = v;
        }
    };
    auto wload = [&](int kc) {
        #pragma unroll
        for (int r = 0; r < WREG; ++r) {
            const int j = tid + r * 256;
            if (j < NWLD) {
                const int tap = j / (OCWG * 4), rem = j % (OCWG * 4);
                const int oc = rem >> 2, e = rem & 3;
                wld[r] = *(const f16x8*)(wgt +
                    (((size_t)kc * 9 + tap) * OCg + oc0 + oc) * 32 + e * 8);
            }
        }
    };
    auto iwrite = [&](int buf) {
        #pragma unroll
        for (int r = 0; r < IREG; ++r) {
            const int i = tid + r * 256;
            if (i < NLD) {
                const int sp = i >> 2, seg = i & 3;
                if constexpr (NORM_IN) {
                    const float f = rS[sp];
                    unsigned* d = (unsigned*)&in_t[buf][sp * ICP + seg * 8];
                    d[0] = pack2f16((float)ild[r][0] * f, (float)ild[r][1] * f);
                    d[1] = pack2f16((float)ild[r][2] * f, (float)ild[r][3] * f);
                    d[2] = pack2f16((float)ild[r][4] * f, (float)ild[r][5] * f);
                    d[3] = pack2f16((float)ild[r][6] * f, (float)ild[r][7] * f);
                } else {
                    *(f16x8*)&in_t[buf][sp * ICP + seg * 8] = ild[r];
                }
            }
        }
    };
    auto wwrite = [&](int buf) {
        #pragma unroll
        for (int r = 0; r < WREG; ++r) {
            const int j = tid + r * 256;
            if (j < NWLD) {
                const int tap = j / (OCWG * 4), rem = j % (OCWG * 4);
                const int oc = rem >> 2, e = rem & 3;
                const int slot = e ^ ((oc >> 1) & 3);
                *(f16x8*)&w_t[buf][tap * WOC + oc * 32 + slot * 8] = wld[r];
            }
        }
    };

    const int prow = wave * 4;      // wave's 4 tile rows

    f32x4 acc[4][NF];
    #pragma unroll
    for (int mf = 0; mf < 4; ++mf)
        #pragma unroll
        for (int nf = 0; nf < NF; ++nf) acc[mf][nf] = (f32x4){0.f, 0.f, 0.f, 0.f};

    // prologue
    iload(0); wload(0);
    if constexpr (NORM_IN) {
        for (int i = tid; i < NSP; i += 256) {
            const int yy = y0 + i / WSp - 1, xx = x0 + i % WSp - 1;
            float sv = 0.f;
            if (yy >= 0 && yy < H && xx >= 0 && xx < W)
                sv = Sin[(size_t)b * HW + (size_t)yy * W + xx];
            rS[i] = 1.f / (sv + EPSV);
        }
        __syncthreads();
    }
    iwrite(0); wwrite(0);
    __syncthreads();

    int cur = 0;
    for (int kc = 0; kc < NCH; ++kc) {
        if (kc + 1 < NCH) { iload(kc + 1); wload(kc + 1); }
        // ---- compute chunk from LDS only ----
        {
            const _Float16* ib = &in_t[cur][0];
            const _Float16* wb = &w_t[cur][0];
            #pragma unroll
            for (int dy = 0; dy < 3; ++dy) {
                #pragma unroll
                for (int dx = 0; dx < 3; ++dx) {
                    const int tap = dy * 3 + dx;
                    f16x8 bfr[NF];
                    #pragma unroll
                    for (int nf = 0; nf < NF; ++nf) {
                        const int oc = nf * 16 + l15;
                        bfr[nf] = *(const f16x8*)(
                            wb + tap * WOC + oc * 32 + (kq ^ ((oc >> 1) & 3)) * 8);
                    }
                    f16x8 afr[4];
                    #pragma unroll
                    for (int mf = 0; mf < 4; ++mf)
                        afr[mf] = *(const f16x8*)(
                            ib + ((prow + mf + dy) * WSp + l15 + dx) * ICP + kq * 8);
                    #pragma unroll
                    for (int mf = 0; mf < 4; ++mf)
                        #pragma unroll
                        for (int nf = 0; nf < NF; ++nf)
                            acc[mf][nf] = __builtin_amdgcn_mfma_f32_16x16x32_f16(
                                afr[mf], bfr[nf], acc[mf][nf], 0, 0, 0);
                }
            }
        }
        if (kc + 1 < NCH) {
            iwrite(cur ^ 1); wwrite(cur ^ 1);
            __syncthreads();
            cur ^= 1;
        }
    }

    // ---- epilogue: lane holds pixels (row prow+mf, cols kq*4..+3) x oc ----
    #pragma unroll
    for (int mf = 0; mf < 4; ++mf) {
        const int gy = y0 + prow + mf;
        const size_t pixbase = (size_t)b * HW + (size_t)gy * W + x0 + kq * 4;
        if constexpr (!UPDATE) {
            #pragma unroll
            for (int nf = 0; nf < NF; ++nf) {
                const int oc = oc0 + nf * 16 + l15;
                if (oc < NW) {
                    #pragma unroll
                    for (int r = 0; r < 4; ++r) {
                        const size_t idx = (pixbase + r) * OST + oc;
                        out[idx] = (_Float16)((float)aux[idx] / (acc[mf][nf][r] + EPSV));
                    }
                }
            }
        } else {
            float s[4] = {0.f, 0.f, 0.f, 0.f};
            #pragma unroll
            for (int nf = 0; nf < NF; ++nf) {
                const int oc = oc0 + nf * 16 + l15;
                #pragma unroll
                for (int r = 0; r < 4; ++r) {
                    const size_t idx = (pixbase + r) * OST + oc;
                    const float hv = (float)out[idx] * acc[mf][nf][r];
                    const _Float16 hq = (_Float16)hv;
                    out[idx] = hq;
                    s[r] += (float)hq;
                }
            }
            #pragma unroll
            for (int mm = 1; mm < 16; mm <<= 1) {
                #pragma unroll
                for (int r = 0; r < 4; ++r) s[r] += __shfl_xor(s[r], mm);
            }
            if (l15 == 0) {
                float* sp_ = Sout + (size_t)split * sstride + pixbase;
                sp_[0] = s[0]; sp_[1] = s[1]; sp_[2] = s[2]; sp_[3] = s[3];
            }
        }
    }
}

// ---------------------------------------------------------------------------
// Block0 update conv (3 -> 64) via im2col MFMA, h f16 RMW.
// ---------------------------------------------------------------------------
__global__ __launch_bounds__(256) void mf0u_kernel(
    const _Float16* __restrict__ ratio4, const _Float16* __restrict__ wB0h,
    _Float16* __restrict__ h, float* __restrict__ Sout, int H, int W)
{
    constexpr int TW = 16;
    __shared__ _Float16 a_t[64 * 72];

    const int tid = threadIdx.x;
    const int lane = tid & 63, wave = tid >> 6;
    const int kq = lane >> 4, l15 = lane & 15;
    const int x0 = blockIdx.x * TW, y0 = blockIdx.y * 4, b = blockIdx.z;
    const int HW = H * W;

    for (int i = tid; i < 64 * 72 / 2; i += 256) ((unsigned*)a_t)[i] = 0;
    __syncthreads();
    for (int i = tid; i < 576; i += 256) {
        const int px = i / 9, tap = i % 9;
        const int py = px / TW, pxx = px % TW;
        const int yy = y0 + py + tap / 3 - 1, xx = x0 + pxx + tap % 3 - 1;
        if (yy >= 0 && yy < H && xx >= 0 && xx < W)
            *(f16x4*)&a_t[px * 72 + tap * 4] =
                *(const f16x4*)(ratio4 + ((size_t)b * HW + (size_t)yy * W + xx) * 4);
    }
    __syncthreads();

    f32x4 acc[4];
    #pragma unroll
    for (int nf = 0; nf < 4; ++nf) acc[nf] = (f32x4){0.f, 0.f, 0.f, 0.f};
    #pragma unroll
    for (int kc = 0; kc < 2; ++kc) {
        const f16x8 afr = *(const f16x8*)&a_t[(wave * 16 + l15) * 72 + kc * 32 + kq * 8];
        #pragma unroll
        for (int nf = 0; nf < 4; ++nf) {
            const f16x8 bfr = *(const f16x8*)(wB0h + (size_t)(nf * 16 + l15) * 64 + kc * 32 + kq * 8);
            acc[nf] = __builtin_amdgcn_mfma_f32_16x16x32_f16(afr, bfr, acc[nf], 0, 0, 0);
        }
    }

    const int pl = wave * 16 + kq * 4;
    const size_t pixbase = (size_t)b * HW + (size_t)(y0 + pl / TW) * W + x0 + pl % TW;
    float s[4] = {0.f, 0.f, 0.f, 0.f};
    #pragma unroll
    for (int nf = 0; nf < 4; ++nf) {
        const int oc = nf * 16 + l15;
        #pragma unroll
        for (int r = 0; r < 4; ++r) {
            const size_t idx = (pixbase + r) * 64 + oc;
            const float hv = (float)h[idx] * acc[nf][r];
            const _Float16 hq = (_Float16)hv;
            h[idx] = hq;
            s[r] += (float)hq;
        }
    }
    #pragma unroll
    for (int mm = 1; mm < 16; mm <<= 1) {
        #pragma unroll
        for (int r = 0; r < 4; ++r) s[r] += __shfl_xor(s[r], mm);
    }
    if (l15 == 0) {
        float* sp_ = Sout + pixbase;
        sp_[0] = s[0]; sp_[1] = s[1]; sp_[2] = s[2]; sp_[3] = s[3];
    }
}

// ---------------------------------------------------------------------------
// posty (MFMA 1x1 conv), two-pass; h f16. Tile = 2 rows x 32 cols.
//   MODE 0: stats partials. MODE 1: pool+BN -> f16 NHWC. MODE 2: fp32 NCHW.
// ---------------------------------------------------------------------------
template<int C, int MODE>
__global__ __launch_bounds__(256) void posty_kernel(
    const _Float16* __restrict__ h, const float* __restrict__ S,
    const _Float16* __restrict__ w1h, const float* __restrict__ bias,
    const float* __restrict__ bnst, float* __restrict__ part,
    void* __restrict__ outp, int H, int W)
{
    constexpr int NF = C / 16, CP = C + 8;
    __shared__ _Float16 a_t[64 * CP];
    __shared__ float rs_t[64];
    __shared__ float sred1[MODE == 0 ? 4 * C : 1];
    __shared__ float sred2[MODE == 0 ? 4 * C : 1];

    const int tid = threadIdx.x;
    const int lane = tid & 63, wave = tid >> 6;
    const int kq = lane >> 4, l15 = lane & 15;
    const int WT = W / 32;
    const int tx = blockIdx.x % WT, ty = blockIdx.x / WT;
    const int b = blockIdx.y;
    const int HW = H * W;

    if (tid < 64) {
        const int gp = (2 * ty + (tid >> 5)) * W + tx * 32 + (tid & 31);
        rs_t[tid] = 1.f / (S[(size_t)b * HW + gp] + EPSV);
    }
    __syncthreads();
    for (int i = tid; i < 64 * (C / 8); i += 256) {
        const int sp = i / (C / 8), seg = i % (C / 8);
        const int gp = (2 * ty + (sp >> 5)) * W + tx * 32 + (sp & 31);
        const f16x8 v = *(const f16x8*)(h + ((size_t)b * HW + gp) * C + seg * 8);
        const float f = rs_t[sp];
        unsigned* d = (unsigned*)&a_t[sp * CP + seg * 8];
        d[0] = pack2f16((float)v[0] * f, (float)v[1] * f);
        d[1] = pack2f16((float)v[2] * f, (float)v[3] * f);
        d[2] = pack2f16((float)v[4] * f, (float)v[5] * f);
        d[3] = pack2f16((float)v[6] * f, (float)v[7] * f);
    }
    __syncthreads();

    f32x4 acc[NF];
    #pragma unroll
    for (int nf = 0; nf < NF; ++nf) acc[nf] = (f32x4){0.f, 0.f, 0.f, 0.f};
    #pragma unroll
    for (int kc = 0; kc < C / 32; ++kc) {
        const f16x8 afr = *(const f16x8*)&a_t[(wave * 16 + l15) * CP + kc * 32 + kq * 8];
        #pragma unroll
        for (int nf = 0; nf < NF; ++nf) {
            const f16x8 bfr = *(const f16x8*)(w1h + (size_t)(nf * 16 + l15) * C + kc * 32 + kq * 8);
            acc[nf] = __builtin_amdgcn_mfma_f32_16x16x32_f16(afr, bfr, acc[nf], 0, 0, 0);
        }
    }

    const int pl = wave * 16 + kq * 4;

    if constexpr (MODE == 0) {
        const int wgid = b * gridDim.x + blockIdx.x;
        #pragma unroll
        for (int nf = 0; nf < NF; ++nf) {
            const int oc = nf * 16 + l15;
            const float bv = bias[oc];
            float s1 = 0.f, s2 = 0.f;
            #pragma unroll
            for (int r = 0; r < 4; ++r) {
                const float y = fmaxf(acc[nf][r] + bv, 0.f);
                s1 += y; s2 += y * y;
            }
            s1 += __shfl_xor(s1, 16); s2 += __shfl_xor(s2, 16);
            s1 += __shfl_xor(s1, 32); s2 += __shfl_xor(s2, 32);
            if (kq == 0) {
                sred1[wave * C + oc] = s1;
                sred2[wave * C + oc] = s2;
            }
        }
        __syncthreads();
        for (int oc = tid; oc < C; oc += 256) {
            const float s1 = sred1[oc] + sred1[C + oc] + sred1[2 * C + oc] + sred1[3 * C + oc];
            const float s2 = sred2[oc] + sred2[C + oc] + sred2[2 * C + oc] + sred2[3 * C + oc];
            part[((size_t)wgid * C + oc) * 2 + 0] = s1;
            part[((size_t)wgid * C + oc) * 2 + 1] = s2;
        }
    } else {
        __syncthreads();        // all A-reads complete; reuse a_t for Y
        #pragma unroll
        for (int nf = 0; nf < NF; ++nf) {
            const int oc = nf * 16 + l15;
            const float bv = bias[oc];
            #pragma unroll
            for (int r = 0; r < 4; ++r)
                a_t[(pl + r) * CP + oc] = (_Float16)fmaxf(acc[nf][r] + bv, 0.f);
        }
        __syncthreads();
        const int Wo = W >> 1;
        for (int i = tid; i < 16 * C; i += 256) {
            int ox, c;
            if constexpr (MODE == 1) { c = i % C; ox = i / C; }
            else                     { ox = i % 16; c = i / 16; }
            const float y00 = (float)a_t[(2 * ox) * CP + c];
            const float y01 = (float)a_t[(2 * ox + 1) * CP + c];
            const float y10 = (float)a_t[(32 + 2 * ox) * CP + c];
            const float y11 = (float)a_t[(32 + 2 * ox + 1) * CP + c];
            const float v = (y00 + y01 + y10 + y11) * 0.25f * bnst[c] + bnst[C + c];
            if constexpr (MODE == 1) {
                ((_Float16*)outp)[((size_t)b * (HW >> 2) + (size_t)ty * Wo + tx * 16 + ox) * C + c] =
                    (_Float16)v;
            } else {
                ((float*)outp)[(((size_t)b * C + c) * (size_t)(H >> 1) + ty) * Wo + tx * 16 + ox] = v;
            }
        }
    }
}

// Reduce partials -> per-channel (scale, shift) for BN affine.
template<int C>
__global__ __launch_bounds__(256) void stats_kernel(const float* __restrict__ part, int nwg, float invM,
                                                    const float* __restrict__ gamma,
                                                    const float* __restrict__ beta,
                                                    float* __restrict__ stats)
{
    const int oc = blockIdx.x;
    const int tid = threadIdx.x;
    float s1 = 0.f, s2 = 0.f;
    for (int w = tid; w < nwg; w += 256) {
        s1 += part[((size_t)w * C + oc) * 2 + 0];
        s2 += part[((size_t)w * C + oc) * 2 + 1];
    }
    __shared__ float r1[4], r2[4];
    #pragma unroll
    for (int m = 32; m; m >>= 1) { s1 += __shfl_xor(s1, m, 64); s2 += __shfl_xor(s2, m, 64); }
    if ((tid & 63) == 0) { r1[tid >> 6] = s1; r2[tid >> 6] = s2; }
    __syncthreads();
    if (tid == 0) {
        s1 = r1[0] + r1[1] + r1[2] + r1[3];
        s2 = r2[0] + r2[1] + r2[2] + r2[3];
        const float mean = s1 * invM;
        const float var  = s2 * invM - mean * mean;
        const float rstd = rsqrtf(var + BNEPS);
        const float scale = gamma[oc] * rstd;
        stats[oc]     = scale;
        stats[C + oc] = beta[oc] - mean * scale;
    }
}

// ---------------------------------------------------------------------------
extern "C" void kernel_launch(void* const* d_in, const int* in_sizes, int n_in,
                              void* d_out, int out_size, void* d_ws, size_t ws_size,
                              hipStream_t stream)
{
    const float* x = (const float*)d_in[0];
    float* ws      = (float*)d_ws;
    float* S       = ws;                    //    262,144 f32
    float* part    = S + 262144;            //  1,048,576 f32
    float* bnstats = part + 1048576;        //        512 f32
    _Float16* h      = (_Float16*)(bnstats + 512); // 16,777,216 f16
    _Float16* xnh    = h + 16777216;               //  4,194,304 f16
    _Float16* ratioh = xnh + 4194304;              //  4,194,304 f16
    _Float16* out0h  = ratioh + 4194304;           //  4,194,304 f16
    _Float16* out1h  = out0h + 4194304;            //  2,097,152 f16
    _Float16* wAh    = out1h + 2097152;            //    294,912 f16
    _Float16* wBh    = wAh + 294912;               //    294,912 f16
    _Float16* w1h    = wBh + 294912;               //     65,536 f16
    _Float16* wA0h   = w1h + 65536;                //      9,216 f16
    _Float16* wB0h   = wA0h + 9216;                //      4,096 f16 (adjacent)

    const int B = 16;

    // ---------------- Block 0: Cin=3, Cout=64, 128x128 ----------------
    {
        const int H = 128, W = 128, HW = H * W, npx = B * HW;
        zero_f16_kernel<<<(9216 + 255) / 256, 256, 0, stream>>>(wA0h, 9216);
        prep_w0_kernel<<<64, 64, 0, stream>>>((const float*)d_in[1], wA0h, wB0h);
        xn0_kernel<<<npx / 256, 256, 0, stream>>>(x, xnh, npx, HW);
        init_h_kernel<<<(npx * 64 + 255) / 256, 256, 0, stream>>>(h, S, npx * 64, npx, 64.f);
        for (int it = 0; it < 5; ++it) {
            mfconv5<64, 16, 1, 4, 4, true, false>
                <<<dim3(8, 8, B), 256, 0, stream>>>(h, wA0h, xnh, ratioh, S, nullptr, H, W, 0);
            mf0u_kernel<<<dim3(8, 32, B), 256, 0, stream>>>(ratioh, wB0h, h, S, H, W);
        }
        prep_w1h_kernel<<<16, 256, 0, stream>>>((const float*)d_in[2], w1h, 64 * 64);
        dim3 pg((W / 32) * (H / 2), B);
        posty_kernel<64, 0><<<pg, 256, 0, stream>>>(h, S, w1h, (const float*)d_in[3],
                                                    nullptr, part, nullptr, H, W);
        stats_kernel<64><<<64, 256, 0, stream>>>(part, pg.x * pg.y, 1.0f / (float)npx,
                                                 (const float*)d_in[4], (const float*)d_in[5], bnstats);
        posty_kernel<64, 1><<<pg, 256, 0, stream>>>(h, S, w1h, (const float*)d_in[3],
                                                    bnstats, nullptr, out0h, H, W);
    }

    // ---------------- Block 1: Cin=64, Cout=128, 64x64 ----------------
    {
        const int H = 64, W = 64, HW = H * W, npx = B * HW;
        prep_w_f16_kernel<64, 128><<<128, 256, 0, stream>>>((const float*)d_in[6], wAh, wBh);
        xn12_kernel<64><<<npx / 256, 256, 0, stream>>>(out0h, xnh, npx);
        init_h_kernel<<<(npx * 128 + 255) / 256, 256, 0, stream>>>(h, S, npx * 128, npx, 128.f);
        for (int it = 0; it < 5; ++it) {
            mfconv5<128, 64, 1, 64, 64, true, false>
                <<<dim3(4, 4, B), 256, 0, stream>>>(h, wAh, xnh, ratioh, S, nullptr, H, W, 0);
            mfconv5<64, 128, 2, 128, 128, false, true>
                <<<dim3(8, 4, B), 256, 0, stream>>>(ratioh, wBh, nullptr, h, nullptr, part, H, W, npx);
            combine_S_kernel<2><<<(npx + 255) / 256, 256, 0, stream>>>(part, S, npx);
        }
        prep_w1h_kernel<<<64, 256, 0, stream>>>((const float*)d_in[7], w1h, 128 * 128);
        dim3 pg((W / 32) * (H / 2), B);
        posty_kernel<128, 0><<<pg, 256, 0, stream>>>(h, S, w1h, (const float*)d_in[8],
                                                     nullptr, part, nullptr, H, W);
        stats_kernel<128><<<128, 256, 0, stream>>>(part, pg.x * pg.y, 1.0f / (float)npx,
                                                   (const float*)d_in[9], (const float*)d_in[10], bnstats);
        posty_kernel<128, 1><<<pg, 256, 0, stream>>>(h, S, w1h, (const float*)d_in[8],
                                                     bnstats, nullptr, out1h, H, W);
    }

    // ---------------- Block 2: Cin=128, Cout=256, 32x32 ----------------
    {
        const int H = 32, W = 32, HW = H * W, npx = B * HW;
        prep_w_f16_kernel<128, 256><<<256, 256, 0, stream>>>((const float*)d_in[11], wAh, wBh);
        xn12_kernel<128><<<npx / 256, 256, 0, stream>>>(out1h, xnh, npx);
        init_h_kernel<<<(npx * 256 + 255) / 256, 256, 0, stream>>>(h, S, npx * 256, npx, 256.f);
        for (int it = 0; it < 5; ++it) {
            mfconv5<256, 128, 2, 128, 128, true, false>
                <<<dim3(4, 2, B), 256, 0, stream>>>(h, wAh, xnh, ratioh, S, nullptr, H, W, 0);
            mfconv5<128, 256, 4, 256, 256, false, true>
                <<<dim3(8, 2, B), 256, 0, stream>>>(ratioh, wBh, nullptr, h, nullptr, part, H, W, npx);
            combine_S_kernel<4><<<(npx + 255) / 256, 256, 0, stream>>>(part, S, npx);
        }
        prep_w1h_kernel<<<256, 256, 0, stream>>>((const float*)d_in[12], w1h, 256 * 256);
        dim3 pg((W / 32) * (H / 2), B);
        posty_kernel<256, 0><<<pg, 256, 0, stream>>>(h, S, w1h, (const float*)d_in[13],
                                                     nullptr, part, nullptr, H, W);
        stats_kernel<256><<<256, 256, 0, stream>>>(part, pg.x * pg.y, 1.0f / (float)npx,
                                                   (const float*)d_in[14], (const float*)d_in[15], bnstats);
        posty_kernel<256, 2><<<pg, 256, 0, stream>>>(h, S, w1h, (const float*)d_in[13],
                                                     bnstats, nullptr, d_out, H, W);
    }
}

// Round 11
// 824.683 us; speedup vs baseline: 2.5036x; 1.1624x over previous
//
#include <hip/hip_runtime.h>

#define EPSV  1e-20f
#define BNEPS 1e-5f

typedef _Float16 f16x8 __attribute__((ext_vector_type(8)));
typedef _Float16 f16x4 __attribute__((ext_vector_type(4)));
typedef float    f32x4 __attribute__((ext_vector_type(4)));

__device__ inline unsigned pack2f16(float a, float b) {
    unsigned short ua = __builtin_bit_cast(unsigned short, (_Float16)a);
    unsigned short ub = __builtin_bit_cast(unsigned short, (_Float16)b);
    return ((unsigned)ub << 16) | ua;
}

// ---------------------------------------------------------------------------
// Weight prep (blocks 1/2): wn = |w|/(sum+eps); chunked GEMM layouts:
//   wBh[kc(ci/32)][tap ][co(COUT)][ci%32]   (update conv: n=co, k=ci)
//   wAh[kc(co/32)][tapf][ci(CIN) ][co%32]   (ratio conv:  n=ci, k=co)
// ---------------------------------------------------------------------------
template<int CIN, int COUT>
__global__ __launch_bounds__(256) void prep_w_f16_kernel(const float* __restrict__ w,
                                                         _Float16* __restrict__ wAh,
                                                         _Float16* __restrict__ wBh)
{
    const int co  = blockIdx.x;
    const int tid = threadIdx.x;
    const int N   = CIN * 9;
    const float* wrow = w + (size_t)co * N;

    float s = 0.f;
    for (int i = tid; i < N; i += 256) s += fabsf(wrow[i]);
    __shared__ float red[4];
    #pragma unroll
    for (int m = 32; m; m >>= 1) s += __shfl_xor(s, m, 64);
    if ((tid & 63) == 0) red[tid >> 6] = s;
    __syncthreads();
    s = red[0] + red[1] + red[2] + red[3];
    const float rn = 1.f / (s + EPSV);

    for (int i = tid; i < N; i += 256) {
        const int ci = i / 9, tap = i % 9;
        const int ky = tap / 3, kx = tap % 3;
        const float v = fabsf(wrow[i]) * rn;
        const int tf = (2 - ky) * 3 + (2 - kx);
        wBh[(((size_t)(ci >> 5) * 9 + tap) * COUT + co) * 32 + (ci & 31)] = (_Float16)v;
        wAh[(((size_t)(co >> 5) * 9 + tf) * CIN + ci) * 32 + (co & 31)] = (_Float16)v;
    }
}

// Block0: wB0h[co][tap*4+ci] (K=36 pad 64, im2col), wA0h[kc][tapf][ci16][co%32]
__global__ __launch_bounds__(256) void zero_f16_kernel(_Float16* __restrict__ a, int n)
{
    const int i = blockIdx.x * 256 + threadIdx.x;
    if (i < n) a[i] = (_Float16)0.f;
}

__global__ __launch_bounds__(64) void prep_w0_kernel(const float* __restrict__ w,
                                                     _Float16* __restrict__ wA0h,
                                                     _Float16* __restrict__ wB0h)
{
    const int co = blockIdx.x, tid = threadIdx.x;  // 64 threads, 1 wave
    float s = (tid < 27) ? fabsf(w[co * 27 + tid]) : 0.f;
    #pragma unroll
    for (int m = 32; m; m >>= 1) s += __shfl_xor(s, m, 64);
    const float rn = 1.f / (s + EPSV);
    if (tid < 27) {
        const int ci = tid / 9, tap = tid % 9, ky = tap / 3, kx = tap % 3;
        const float v = fabsf(w[co * 27 + tid]) * rn;
        const int tf = (2 - ky) * 3 + (2 - kx);
        wB0h[co * 64 + tap * 4 + ci] = (_Float16)v;
        wA0h[(((co >> 5) * 9 + tf) * 16 + ci) * 32 + (co & 31)] = (_Float16)v;
    }
}

__global__ __launch_bounds__(256) void prep_w1h_kernel(const float* __restrict__ w1,
                                                       _Float16* __restrict__ w1h, int n)
{
    const int i = blockIdx.x * 256 + threadIdx.x;
    if (i < n) w1h[i] = (_Float16)w1[i];
}

// ---------------------------------------------------------------------------
// xn prep (block0 only): x NCHW fp32 -> xn [pix][4] f16 (ch3=0).
// ---------------------------------------------------------------------------
__global__ __launch_bounds__(256) void xn0_kernel(const float* __restrict__ x,
                                                  _Float16* __restrict__ xn4,
                                                  int npx, int HW)
{
    const int p = blockIdx.x * 256 + threadIdx.x;
    if (p >= npx) return;
    const int b = p / HW, r = p % HW;
    const float* ip = x + (size_t)b * 3 * HW + r;
    const float v0 = fmaxf(ip[0], 0.f), v1 = fmaxf(ip[HW], 0.f), v2 = fmaxf(ip[2 * HW], 0.f);
    const float rs = 1.f / (v0 + v1 + v2 + EPSV);
    unsigned* d = (unsigned*)(xn4 + (size_t)p * 4);
    d[0] = pack2f16(v0 * rs, v1 * rs);
    d[1] = pack2f16(v2 * rs, 0.f);
}

// ---------------------------------------------------------------------------
// mfconv5: NHWC f16 MFMA implicit-GEMM 3x3 conv, high-reuse register tiling.
//   Tile = 16x16 px, 4 waves; wave owns 4 M-frags (64 px) x NF oc-frags.
//   Per-32k chunks, input+weights double-buffered in LDS (one barrier/chunk).
//   NORM_IN: input scaled by 1/(Sum_k Sin_k + eps) while staging (ratio conv).
//   FIRST && NORM_IN: stage CONSTANT 1/ICg (h==1, S==C) -- no input/S reads.
//   !UPDATE: out = aux/(acc+eps) f16, stride OST, only oc<NW written.
//   UPDATE : FIRST ? h = acc : h *= acc (f16 RMW); S partials at split*sstride.
// Weights global: [kc][tap][n(OCg)][32]; LDS [tap][oc][32] XOR-swizzled.
// ---------------------------------------------------------------------------
template<int ICg, int OCg, int NSPLIT, int OST, int NW, int NSIN,
         bool NORM_IN, bool UPDATE, bool FIRST>
__global__ __launch_bounds__(256, 1) void mfconv5(
    const _Float16* __restrict__ in, const _Float16* __restrict__ wgt,
    const _Float16* __restrict__ aux, _Float16* __restrict__ out,
    const float* __restrict__ Sin, float* __restrict__ Sout,
    int H, int W, int sstride)
{
    constexpr bool CSTAGE = FIRST && NORM_IN;   // constant input staging
    constexpr int OCWG = OCg / NSPLIT;
    constexpr int NF = OCWG / 16;
    constexpr int HS = 18, WSp = 18, NSP = HS * WSp;   // 16x16 tile + halo
    constexpr int ICP = 40;
    constexpr int NCH = ICg / 32;
    constexpr int LS = (NSPLIT == 4) ? 2 : (NSPLIT == 2) ? 1 : 0;
    constexpr int NLD = NSP * 4;
    constexpr int IREG = (NLD + 255) / 256;
    constexpr int WOC = OCWG * 32;
    constexpr int NWLD = 9 * OCWG * 4;
    constexpr int WREG = (NWLD + 255) / 256;
    static_assert(OCWG % 16 == 0 && ICg % 32 == 0, "cfg");

    __shared__ _Float16 in_t[CSTAGE ? 1 : 2][NSP * ICP];
    __shared__ _Float16 w_t[2][9 * WOC];
    __shared__ float rS[(NORM_IN && !FIRST) ? NSP : 1];

    const int tid = threadIdx.x;
    const int lane = tid & 63, wave = tid >> 6;
    const int kq = lane >> 4, l15 = lane & 15;
    const int split = blockIdx.x & (NSPLIT - 1);
    const int tx = blockIdx.x >> LS;
    const int x0 = tx * 16, y0 = blockIdx.y * 16, b = blockIdx.z;
    const int HW = H * W;
    const int oc0 = split * OCWG;

    f16x8 ild[CSTAGE ? 1 : IREG];
    f16x8 wld[WREG];

    auto iload = [&](int kc) {
        #pragma unroll
        for (int r = 0; r < IREG; ++r) {
            const int i = tid + r * 256;
            f16x8 v = {0, 0, 0, 0, 0, 0, 0, 0};
            if (i < NLD) {
                const int sp = i >> 2, seg = i & 3;
                const int yy = y0 + sp / WSp - 1, xx = x0 + sp % WSp - 1;
                if (yy >= 0 && yy < H && xx >= 0 && xx < W)
                    v = __builtin_nontemporal_load((const f16x8*)(in +
                        ((size_t)b * HW + (size_t)yy * W + xx) * ICg + kc * 32 + seg * 8));
            }
            ild[r] = v;
        }
    };
    auto wload = [&](int kc) {
        #pragma unroll
        for (int r = 0; r < WREG; ++r) {
            const int j = tid + r * 256;
            if (j < NWLD) {
                const int tap = j / (OCWG * 4), rem = j % (OCWG * 4);
                const int oc = rem >> 2, e = rem & 3;
                wld[r] = *(const f16x8*)(wgt +
                    (((size_t)kc * 9 + tap) * OCg + oc0 + oc) * 32 + e * 8);
            }
        }
    };
    auto iwrite = [&](int buf) {
        #pragma unroll
        for (int r = 0; r < IREG; ++r) {
            const int i = tid + r * 256;
            if (i < NLD) {
                const int sp = i >> 2, seg = i & 3;
                if constexpr (NORM_IN && !FIRST) {
                    const float f = rS[sp];
                    unsigned* d = (unsigned*)&in_t[buf][sp * ICP + seg * 8];
                    d[0] = pack2f16((float)ild[r][0] * f, (float)ild[r][1] * f);
                    d[1] = pack2f16((float)ild[r][2] * f, (float)ild[r][3] * f);
                    d[2] = pack2f16((float)ild[r][4] * f, (float)ild[r][5] * f);
                    d[3] = pack2f16((float)ild[r][6] * f, (float)ild[r][7] * f);
                } else {
                    *(f16x8*)&in_t[buf][sp * ICP + seg * 8] = ild[r];
                }
            }
        }
    };
    auto wwrite = [&](int buf) {
        #pragma unroll
        for (int r = 0; r < WREG; ++r) {
            const int j = tid + r * 256;
            if (j < NWLD) {
                const int tap = j / (OCWG * 4), rem = j % (OCWG * 4);
                const int oc = rem >> 2, e = rem & 3;
                const int slot = e ^ ((oc >> 1) & 3);
                *(f16x8*)&w_t[buf][tap * WOC + oc * 32 + slot * 8] = wld[r];
            }
        }
    };

    const int prow = wave * 4;

    f32x4 acc[4][NF];
    #pragma unroll
    for (int mf = 0; mf < 4; ++mf)
        #pragma unroll
        for (int nf = 0; nf < NF; ++nf) acc[mf][nf] = (f32x4){0.f, 0.f, 0.f, 0.f};

    // ---- prologue ----
    if constexpr (!CSTAGE) iload(0);
    wload(0);
    if constexpr (NORM_IN && !FIRST) {
        for (int i = tid; i < NSP; i += 256) {
            const int yy = y0 + i / WSp - 1, xx = x0 + i % WSp - 1;
            float sv = 0.f;
            if (yy >= 0 && yy < H && xx >= 0 && xx < W) {
                const size_t pix = (size_t)b * HW + (size_t)yy * W + xx;
                #pragma unroll
                for (int k = 0; k < NSIN; ++k) sv += Sin[(size_t)k * sstride + pix];
            }
            rS[i] = 1.f / (sv + EPSV);
        }
        __syncthreads();
    }
    if constexpr (CSTAGE) {
        const unsigned cpk = pack2f16(1.0f / (float)ICg, 1.0f / (float)ICg);
        for (int i = tid; i < NSP; i += 256) {
            const int yy = y0 + i / WSp - 1, xx = x0 + i % WSp - 1;
            const bool ok = (yy >= 0 && yy < H && xx >= 0 && xx < W);
            unsigned* d = (unsigned*)&in_t[0][i * ICP];
            #pragma unroll
            for (int seg = 0; seg < 16; ++seg) d[seg] = ok ? cpk : 0u;
        }
    } else {
        iwrite(0);
    }
    wwrite(0);
    __syncthreads();

    int cur = 0;
    for (int kc = 0; kc < NCH; ++kc) {
        if (kc + 1 < NCH) {
            if constexpr (!CSTAGE) iload(kc + 1);
            wload(kc + 1);
        }
        // ---- compute chunk from LDS only ----
        {
            const _Float16* ib = &in_t[CSTAGE ? 0 : cur][0];
            const _Float16* wb = &w_t[cur][0];
            #pragma unroll
            for (int dy = 0; dy < 3; ++dy) {
                #pragma unroll
                for (int dx = 0; dx < 3; ++dx) {
                    const int tap = dy * 3 + dx;
                    f16x8 bfr[NF];
                    #pragma unroll
                    for (int nf = 0; nf < NF; ++nf) {
                        const int oc = nf * 16 + l15;
                        bfr[nf] = *(const f16x8*)(
                            wb + tap * WOC + oc * 32 + (kq ^ ((oc >> 1) & 3)) * 8);
                    }
                    f16x8 afr[4];
                    #pragma unroll
                    for (int mf = 0; mf < 4; ++mf)
                        afr[mf] = *(const f16x8*)(
                            ib + ((prow + mf + dy) * WSp + l15 + dx) * ICP + kq * 8);
                    #pragma unroll
                    for (int mf = 0; mf < 4; ++mf)
                        #pragma unroll
                        for (int nf = 0; nf < NF; ++nf)
                            acc[mf][nf] = __builtin_amdgcn_mfma_f32_16x16x32_f16(
                                afr[mf], bfr[nf], acc[mf][nf], 0, 0, 0);
                }
            }
        }
        if (kc + 1 < NCH) {
            if constexpr (!CSTAGE) iwrite(cur ^ 1);
            wwrite(cur ^ 1);
            __syncthreads();
            cur ^= 1;
        }
    }

    // ---- epilogue ----
    #pragma unroll
    for (int mf = 0; mf < 4; ++mf) {
        const int gy = y0 + prow + mf;
        const size_t pixbase = (size_t)b * HW + (size_t)gy * W + x0 + kq * 4;
        if constexpr (!UPDATE) {
            #pragma unroll
            for (int nf = 0; nf < NF; ++nf) {
                const int oc = oc0 + nf * 16 + l15;
                if (oc < NW) {
                    #pragma unroll
                    for (int r = 0; r < 4; ++r) {
                        const size_t idx = (pixbase + r) * OST + oc;
                        out[idx] = (_Float16)((float)aux[idx] / (acc[mf][nf][r] + EPSV));
                    }
                }
            }
        } else {
            float s[4] = {0.f, 0.f, 0.f, 0.f};
            #pragma unroll
            for (int nf = 0; nf < NF; ++nf) {
                const int oc = oc0 + nf * 16 + l15;
                #pragma unroll
                for (int r = 0; r < 4; ++r) {
                    const size_t idx = (pixbase + r) * OST + oc;
                    float hv;
                    if constexpr (FIRST) hv = acc[mf][nf][r];
                    else                 hv = (float)out[idx] * acc[mf][nf][r];
                    const _Float16 hq = (_Float16)hv;
                    out[idx] = hq;
                    s[r] += (float)hq;
                }
            }
            #pragma unroll
            for (int mm = 1; mm < 16; mm <<= 1) {
                #pragma unroll
                for (int r = 0; r < 4; ++r) s[r] += __shfl_xor(s[r], mm);
            }
            if (l15 == 0) {
                float* sp_ = Sout + (size_t)split * sstride + pixbase;
                sp_[0] = s[0]; sp_[1] = s[1]; sp_[2] = s[2]; sp_[3] = s[3];
            }
        }
    }
}

// ---------------------------------------------------------------------------
// Block0 update conv (3 -> 64) via im2col MFMA, h f16 (FIRST: write, else RMW).
// ---------------------------------------------------------------------------
template<bool FIRST>
__global__ __launch_bounds__(256) void mf0u_kernel(
    const _Float16* __restrict__ ratio4, const _Float16* __restrict__ wB0h,
    _Float16* __restrict__ h, float* __restrict__ Sout, int H, int W)
{
    constexpr int TW = 16;
    __shared__ _Float16 a_t[64 * 72];

    const int tid = threadIdx.x;
    const int lane = tid & 63, wave = tid >> 6;
    const int kq = lane >> 4, l15 = lane & 15;
    const int x0 = blockIdx.x * TW, y0 = blockIdx.y * 4, b = blockIdx.z;
    const int HW = H * W;

    for (int i = tid; i < 64 * 72 / 2; i += 256) ((unsigned*)a_t)[i] = 0;
    __syncthreads();
    for (int i = tid; i < 576; i += 256) {
        const int px = i / 9, tap = i % 9;
        const int py = px / TW, pxx = px % TW;
        const int yy = y0 + py + tap / 3 - 1, xx = x0 + pxx + tap % 3 - 1;
        if (yy >= 0 && yy < H && xx >= 0 && xx < W)
            *(f16x4*)&a_t[px * 72 + tap * 4] =
                *(const f16x4*)(ratio4 + ((size_t)b * HW + (size_t)yy * W + xx) * 4);
    }
    __syncthreads();

    f32x4 acc[4];
    #pragma unroll
    for (int nf = 0; nf < 4; ++nf) acc[nf] = (f32x4){0.f, 0.f, 0.f, 0.f};
    #pragma unroll
    for (int kc = 0; kc < 2; ++kc) {
        const f16x8 afr = *(const f16x8*)&a_t[(wave * 16 + l15) * 72 + kc * 32 + kq * 8];
        #pragma unroll
        for (int nf = 0; nf < 4; ++nf) {
            const f16x8 bfr = *(const f16x8*)(wB0h + (size_t)(nf * 16 + l15) * 64 + kc * 32 + kq * 8);
            acc[nf] = __builtin_amdgcn_mfma_f32_16x16x32_f16(afr, bfr, acc[nf], 0, 0, 0);
        }
    }

    const int pl = wave * 16 + kq * 4;
    const size_t pixbase = (size_t)b * HW + (size_t)(y0 + pl / TW) * W + x0 + pl % TW;
    float s[4] = {0.f, 0.f, 0.f, 0.f};
    #pragma unroll
    for (int nf = 0; nf < 4; ++nf) {
        const int oc = nf * 16 + l15;
        #pragma unroll
        for (int r = 0; r < 4; ++r) {
            const size_t idx = (pixbase + r) * 64 + oc;
            float hv;
            if constexpr (FIRST) hv = acc[nf][r];
            else                 hv = (float)h[idx] * acc[nf][r];
            const _Float16 hq = (_Float16)hv;
            h[idx] = hq;
            s[r] += (float)hq;
        }
    }
    #pragma unroll
    for (int mm = 1; mm < 16; mm <<= 1) {
        #pragma unroll
        for (int r = 0; r < 4; ++r) s[r] += __shfl_xor(s[r], mm);
    }
    if (l15 == 0) {
        float* sp_ = Sout + pixbase;
        sp_[0] = s[0]; sp_[1] = s[1]; sp_[2] = s[2]; sp_[3] = s[3];
    }
}

// ---------------------------------------------------------------------------
// posty (MFMA 1x1 conv), two-pass; h f16; S = sum of NSIN partials.
//   MODE 0: stats partials.
//   MODE 1: pool+BN -> relu+L1-normalize -> xn f16 NHWC (next block input).
//   MODE 2: pool+BN -> fp32 NCHW (d_out).
// ---------------------------------------------------------------------------
template<int C, int MODE, int NSIN>
__global__ __launch_bounds__(256) void posty_kernel(
    const _Float16* __restrict__ h, const float* __restrict__ S,
    const _Float16* __restrict__ w1h, const float* __restrict__ bias,
    const float* __restrict__ bnst, float* __restrict__ part,
    void* __restrict__ outp, int H, int W, int sst)
{
    constexpr int NF = C / 16, CP = C + 8;
    __shared__ _Float16 a_t[64 * CP];
    __shared__ float rs_t[64];
    __shared__ float sred1[MODE == 0 ? 4 * C : 1];
    __shared__ float sred2[MODE == 0 ? 4 * C : 1];
    __shared__ float pool_t[MODE == 1 ? 16 * (C + 1) : 1];

    const int tid = threadIdx.x;
    const int lane = tid & 63, wave = tid >> 6;
    const int kq = lane >> 4, l15 = lane & 15;
    const int WT = W / 32;
    const int tx = blockIdx.x % WT, ty = blockIdx.x / WT;
    const int b = blockIdx.y;
    const int HW = H * W;

    if (tid < 64) {
        const int gp = (2 * ty + (tid >> 5)) * W + tx * 32 + (tid & 31);
        float sv = 0.f;
        #pragma unroll
        for (int k = 0; k < NSIN; ++k) sv += S[(size_t)k * sst + (size_t)b * HW + gp];
        rs_t[tid] = 1.f / (sv + EPSV);
    }
    __syncthreads();
    for (int i = tid; i < 64 * (C / 8); i += 256) {
        const int sp = i / (C / 8), seg = i % (C / 8);
        const int gp = (2 * ty + (sp >> 5)) * W + tx * 32 + (sp & 31);
        const f16x8 v = *(const f16x8*)(h + ((size_t)b * HW + gp) * C + seg * 8);
        const float f = rs_t[sp];
        unsigned* d = (unsigned*)&a_t[sp * CP + seg * 8];
        d[0] = pack2f16((float)v[0] * f, (float)v[1] * f);
        d[1] = pack2f16((float)v[2] * f, (float)v[3] * f);
        d[2] = pack2f16((float)v[4] * f, (float)v[5] * f);
        d[3] = pack2f16((float)v[6] * f, (float)v[7] * f);
    }
    __syncthreads();

    f32x4 acc[NF];
    #pragma unroll
    for (int nf = 0; nf < NF; ++nf) acc[nf] = (f32x4){0.f, 0.f, 0.f, 0.f};
    #pragma unroll
    for (int kc = 0; kc < C / 32; ++kc) {
        const f16x8 afr = *(const f16x8*)&a_t[(wave * 16 + l15) * CP + kc * 32 + kq * 8];
        #pragma unroll
        for (int nf = 0; nf < NF; ++nf) {
            const f16x8 bfr = *(const f16x8*)(w1h + (size_t)(nf * 16 + l15) * C + kc * 32 + kq * 8);
            acc[nf] = __builtin_amdgcn_mfma_f32_16x16x32_f16(afr, bfr, acc[nf], 0, 0, 0);
        }
    }

    const int pl = wave * 16 + kq * 4;

    if constexpr (MODE == 0) {
        const int wgid = b * gridDim.x + blockIdx.x;
        #pragma unroll
        for (int nf = 0; nf < NF; ++nf) {
            const int oc = nf * 16 + l15;
            const float bv = bias[oc];
            float s1 = 0.f, s2 = 0.f;
            #pragma unroll
            for (int r = 0; r < 4; ++r) {
                const float y = fmaxf(acc[nf][r] + bv, 0.f);
                s1 += y; s2 += y * y;
            }
            s1 += __shfl_xor(s1, 16); s2 += __shfl_xor(s2, 16);
            s1 += __shfl_xor(s1, 32); s2 += __shfl_xor(s2, 32);
            if (kq == 0) {
                sred1[wave * C + oc] = s1;
                sred2[wave * C + oc] = s2;
            }
        }
        __syncthreads();
        for (int oc = tid; oc < C; oc += 256) {
            const float s1 = sred1[oc] + sred1[C + oc] + sred1[2 * C + oc] + sred1[3 * C + oc];
            const float s2 = sred2[oc] + sred2[C + oc] + sred2[2 * C + oc] + sred2[3 * C + oc];
            part[((size_t)wgid * C + oc) * 2 + 0] = s1;
            part[((size_t)wgid * C + oc) * 2 + 1] = s2;
        }
    } else {
        __syncthreads();        // all A-reads complete; reuse a_t for Y
        #pragma unroll
        for (int nf = 0; nf < NF; ++nf) {
            const int oc = nf * 16 + l15;
            const float bv = bias[oc];
            #pragma unroll
            for (int r = 0; r < 4; ++r)
                a_t[(pl + r) * CP + oc] = (_Float16)fmaxf(acc[nf][r] + bv, 0.f);
        }
        __syncthreads();
        const int Wo = W >> 1;
        if constexpr (MODE == 2) {
            for (int i = tid; i < 16 * C; i += 256) {
                const int ox = i % 16, c = i / 16;
                const float y00 = (float)a_t[(2 * ox) * CP + c];
                const float y01 = (float)a_t[(2 * ox + 1) * CP + c];
                const float y10 = (float)a_t[(32 + 2 * ox) * CP + c];
                const float y11 = (float)a_t[(32 + 2 * ox + 1) * CP + c];
                const float v = (y00 + y01 + y10 + y11) * 0.25f * bnst[c] + bnst[C + c];
                ((float*)outp)[(((size_t)b * C + c) * (size_t)(H >> 1) + ty) * Wo + tx * 16 + ox] = v;
            }
        } else {
            // pool + BN -> pool_t, then per-pixel relu + L1-normalize -> xn
            for (int i = tid; i < 16 * C; i += 256) {
                const int ox = i / C, c = i % C;
                const float y00 = (float)a_t[(2 * ox) * CP + c];
                const float y01 = (float)a_t[(2 * ox + 1) * CP + c];
                const float y10 = (float)a_t[(32 + 2 * ox) * CP + c];
                const float y11 = (float)a_t[(32 + 2 * ox + 1) * CP + c];
                pool_t[ox * (C + 1) + c] =
                    fmaxf((y00 + y01 + y10 + y11) * 0.25f * bnst[c] + bnst[C + c], 0.f);
            }
            __syncthreads();
            const int px = tid >> 4, prt = tid & 15;   // 16 px x 16 lanes (within-wave)
            float ps = 0.f;
            for (int c = prt; c < C; c += 16) ps += pool_t[px * (C + 1) + c];
            ps += __shfl_xor(ps, 1); ps += __shfl_xor(ps, 2);
            ps += __shfl_xor(ps, 4); ps += __shfl_xor(ps, 8);
            const float rs = 1.f / (ps + EPSV);
            _Float16* xo = (_Float16*)outp;
            const size_t obase = ((size_t)b * (HW >> 2) + (size_t)ty * Wo + tx * 16 + px) * C;
            for (int c = prt; c < C; c += 16)
                xo[obase + c] = (_Float16)(pool_t[px * (C + 1) + c] * rs);
        }
    }
}

// Reduce partials -> per-channel (scale, shift) for BN affine.
template<int C>
__global__ __launch_bounds__(256) void stats_kernel(const float* __restrict__ part, int nwg, float invM,
                                                    const float* __restrict__ gamma,
                                                    const float* __restrict__ beta,
                                                    float* __restrict__ stats)
{
    const int oc = blockIdx.x;
    const int tid = threadIdx.x;
    float s1 = 0.f, s2 = 0.f;
    for (int w = tid; w < nwg; w += 256) {
        s1 += part[((size_t)w * C + oc) * 2 + 0];
        s2 += part[((size_t)w * C + oc) * 2 + 1];
    }
    __shared__ float r1[4], r2[4];
    #pragma unroll
    for (int m = 32; m; m >>= 1) { s1 += __shfl_xor(s1, m, 64); s2 += __shfl_xor(s2, m, 64); }
    if ((tid & 63) == 0) { r1[tid >> 6] = s1; r2[tid >> 6] = s2; }
    __syncthreads();
    if (tid == 0) {
        s1 = r1[0] + r1[1] + r1[2] + r1[3];
        s2 = r2[0] + r2[1] + r2[2] + r2[3];
        const float mean = s1 * invM;
        const float var  = s2 * invM - mean * mean;
        const float rstd = rsqrtf(var + BNEPS);
        const float scale = gamma[oc] * rstd;
        stats[oc]     = scale;
        stats[C + oc] = beta[oc] - mean * scale;
    }
}

// ---------------------------------------------------------------------------
extern "C" void kernel_launch(void* const* d_in, const int* in_sizes, int n_in,
                              void* d_out, int out_size, void* d_ws, size_t ws_size,
                              hipStream_t stream)
{
    const float* x = (const float*)d_in[0];
    float* ws      = (float*)d_ws;
    float* S       = ws;                    //    262,144 f32 (S / S-partials)
    float* part    = S + 262144;            //  1,048,576 f32 (posty BN partials)
    float* bnstats = part + 1048576;        //        512 f32
    _Float16* h      = (_Float16*)(bnstats + 512); // 16,777,216 f16
    _Float16* xnh    = h + 16777216;               //  4,194,304 f16
    _Float16* ratioh = xnh + 4194304;              //  4,194,304 f16
    _Float16* wAh    = ratioh + 4194304;           //    294,912 f16
    _Float16* wBh    = wAh + 294912;               //    294,912 f16
    _Float16* w1h    = wBh + 294912;               //     65,536 f16
    _Float16* wA0h   = w1h + 65536;                //      9,216 f16
    _Float16* wB0h   = wA0h + 9216;                //      4,096 f16

    const int B = 16;

    // ---------------- Block 0: Cin=3, Cout=64, 128x128 ----------------
    {
        const int H = 128, W = 128, HW = H * W, npx = B * HW;
        zero_f16_kernel<<<(9216 + 255) / 256, 256, 0, stream>>>(wA0h, 9216);
        prep_w0_kernel<<<64, 64, 0, stream>>>((const float*)d_in[1], wA0h, wB0h);
        xn0_kernel<<<npx / 256, 256, 0, stream>>>(x, xnh, npx, HW);
        // iter 1: constant-staged ratio + write-only update (h0==1, S0==64)
        mfconv5<64, 16, 1, 4, 4, 1, true, false, true>
            <<<dim3(8, 8, B), 256, 0, stream>>>(h, wA0h, xnh, ratioh, S, nullptr, H, W, npx);
        mf0u_kernel<true><<<dim3(8, 32, B), 256, 0, stream>>>(ratioh, wB0h, h, S, H, W);
        for (int it = 1; it < 5; ++it) {
            mfconv5<64, 16, 1, 4, 4, 1, true, false, false>
                <<<dim3(8, 8, B), 256, 0, stream>>>(h, wA0h, xnh, ratioh, S, nullptr, H, W, npx);
            mf0u_kernel<false><<<dim3(8, 32, B), 256, 0, stream>>>(ratioh, wB0h, h, S, H, W);
        }
        prep_w1h_kernel<<<16, 256, 0, stream>>>((const float*)d_in[2], w1h, 64 * 64);
        dim3 pg((W / 32) * (H / 2), B);
        posty_kernel<64, 0, 1><<<pg, 256, 0, stream>>>(h, S, w1h, (const float*)d_in[3],
                                                       nullptr, part, nullptr, H, W, npx);
        stats_kernel<64><<<64, 256, 0, stream>>>(part, pg.x * pg.y, 1.0f / (float)npx,
                                                 (const float*)d_in[4], (const float*)d_in[5], bnstats);
        posty_kernel<64, 1, 1><<<pg, 256, 0, stream>>>(h, S, w1h, (const float*)d_in[3],
                                                       bnstats, nullptr, xnh, H, W, npx);  // -> xn for block1
    }

    // ---------------- Block 1: Cin=64, Cout=128, 64x64 ----------------
    {
        const int H = 64, W = 64, HW = H * W, npx = B * HW;
        prep_w_f16_kernel<64, 128><<<128, 256, 0, stream>>>((const float*)d_in[6], wAh, wBh);
        mfconv5<128, 64, 1, 64, 64, 1, true, false, true>
            <<<dim3(4, 4, B), 256, 0, stream>>>(h, wAh, xnh, ratioh, S, nullptr, H, W, npx);
        mfconv5<64, 128, 2, 128, 128, 1, false, true, true>
            <<<dim3(8, 4, B), 256, 0, stream>>>(ratioh, wBh, nullptr, h, nullptr, S, H, W, npx);
        for (int it = 1; it < 5; ++it) {
            mfconv5<128, 64, 1, 64, 64, 2, true, false, false>
                <<<dim3(4, 4, B), 256, 0, stream>>>(h, wAh, xnh, ratioh, S, nullptr, H, W, npx);
            mfconv5<64, 128, 2, 128, 128, 1, false, true, false>
                <<<dim3(8, 4, B), 256, 0, stream>>>(ratioh, wBh, nullptr, h, nullptr, S, H, W, npx);
        }
        prep_w1h_kernel<<<64, 256, 0, stream>>>((const float*)d_in[7], w1h, 128 * 128);
        dim3 pg((W / 32) * (H / 2), B);
        posty_kernel<128, 0, 2><<<pg, 256, 0, stream>>>(h, S, w1h, (const float*)d_in[8],
                                                        nullptr, part, nullptr, H, W, npx);
        stats_kernel<128><<<128, 256, 0, stream>>>(part, pg.x * pg.y, 1.0f / (float)npx,
                                                   (const float*)d_in[9], (const float*)d_in[10], bnstats);
        posty_kernel<128, 1, 2><<<pg, 256, 0, stream>>>(h, S, w1h, (const float*)d_in[8],
                                                        bnstats, nullptr, xnh, H, W, npx); // -> xn for block2
    }

    // ---------------- Block 2: Cin=128, Cout=256, 32x32 ----------------
    {
        const int H = 32, W = 32, HW = H * W, npx = B * HW;
        prep_w_f16_kernel<128, 256><<<256, 256, 0, stream>>>((const float*)d_in[11], wAh, wBh);
        mfconv5<256, 128, 4, 128, 128, 1, true, false, true>
            <<<dim3(8, 2, B), 256, 0, stream>>>(h, wAh, xnh, ratioh, S, nullptr, H, W, npx);
        mfconv5<128, 256, 4, 256, 256, 1, false, true, true>
            <<<dim3(8, 2, B), 256, 0, stream>>>(ratioh, wBh, nullptr, h, nullptr, S, H, W, npx);
        for (int it = 1; it < 5; ++it) {
            mfconv5<256, 128, 4, 128, 128, 4, true, false, false>
                <<<dim3(8, 2, B), 256, 0, stream>>>(h, wAh, xnh, ratioh, S, nullptr, H, W, npx);
            mfconv5<128, 256, 4, 256, 256, 1, false, true, false>
                <<<dim3(8, 2, B), 256, 0, stream>>>(ratioh, wBh, nullptr, h, nullptr, S, H, W, npx);
        }
        prep_w1h_kernel<<<256, 256, 0, stream>>>((const float*)d_in[12], w1h, 256 * 256);
        dim3 pg((W / 32) * (H / 2), B);
        posty_kernel<256, 0, 4><<<pg, 256, 0, stream>>>(h, S, w1h, (const float*)d_in[13],
                                                        nullptr, part, nullptr, H, W, npx);
        stats_kernel<256><<<256, 256, 0, stream>>>(part, pg.x * pg.y, 1.0f / (float)npx,
                                                   (const float*)d_in[14], (const float*)d_in[15], bnstats);
        posty_kernel<256, 2, 4><<<pg, 256, 0, stream>>>(h, S, w1h, (const float*)d_in[13],
                                                        bnstats, nullptr, d_out, H, W, npx);
    }
}